// Round 1
// baseline (689.807 us; speedup 1.0000x reference)
//
#include <hip/hip_runtime.h>
#include <stdint.h>

#define NB 8
#define SS 2048
#define DD 256
#define NEGV -1e9f

typedef __attribute__((ext_vector_type(8))) __bf16 bf16x8;
typedef __attribute__((ext_vector_type(4))) float f32x4;

union U16 { uint4 u; bf16x8 b; };

__device__ __forceinline__ unsigned short tobf(float v) {
  union { float f; uint32_t u; } c; c.f = v;
  uint32_t r = (c.u + 0x7fffu + ((c.u >> 16) & 1u)) >> 16;
  return (unsigned short)r;
}

// ---------------- LayerNorm (f32 in -> bf16 out), one wave per row ----------
__global__ void ln_kernel(const float* __restrict__ in, const float* __restrict__ w,
                          const float* __restrict__ bparm, unsigned short* __restrict__ outb) {
  int row = blockIdx.x * 4 + (threadIdx.x >> 6);
  int lane = threadIdx.x & 63;
  const float* xr = in + (size_t)row * DD;
  float4 v = *(const float4*)(xr + lane * 4);
  float s = v.x + v.y + v.z + v.w;
  float s2 = v.x * v.x + v.y * v.y + v.z * v.z + v.w * v.w;
#pragma unroll
  for (int m = 1; m < 64; m <<= 1) { s += __shfl_xor(s, m); s2 += __shfl_xor(s2, m); }
  float mu = s * (1.f / DD);
  float var = s2 * (1.f / DD) - mu * mu;
  float rs = rsqrtf(var + 1e-5f);
  float4 wv = *(const float4*)(w + lane * 4);
  float4 bv = *(const float4*)(bparm + lane * 4);
  ushort4 o;
  o.x = tobf((v.x - mu) * rs * wv.x + bv.x);
  o.y = tobf((v.y - mu) * rs * wv.y + bv.y);
  o.z = tobf((v.z - mu) * rs * wv.z + bv.z);
  o.w = tobf((v.w - mu) * rs * wv.w + bv.w);
  *(ushort4*)(outb + (size_t)row * DD + lane * 4) = o;
}

// ---------------- bf16 [B,S,D] -> [B,D,S] transpose, 64x64 LDS tiles --------
__global__ void transpose_kernel(const unsigned short* __restrict__ in,
                                 unsigned short* __restrict__ out) {
  __shared__ unsigned short tile[64][72];  // 72*2=144B rows keep 16B alignment
  int bid = blockIdx.x;
  int b = bid >> 7;
  int rest = bid & 127;           // 32 s-tiles * 4 d-tiles
  int st = rest >> 2, dt = rest & 3;
  int s0 = st * 64, d0 = dt * 64;
  int t = threadIdx.x;
  int r = t >> 2, cs = (t & 3) * 16;
  const unsigned short* src = in + ((size_t)b * SS + s0 + r) * DD + d0 + cs;
  *(uint4*)&tile[r][cs] = *(const uint4*)src;
  *(uint4*)&tile[r][cs + 8] = *(const uint4*)(src + 8);
  __syncthreads();
  union { unsigned short us[16]; uint4 u[2]; } tmp;
  int dr = t >> 2, sseg = (t & 3) * 16;
#pragma unroll
  for (int j = 0; j < 16; ++j) tmp.us[j] = tile[sseg + j][dr];
  unsigned short* dst = out + ((size_t)b * DD + d0 + dr) * SS + s0 + sseg;
  *(uint4*)dst = tmp.u[0];
  *(uint4*)(dst + 8) = tmp.u[1];
}

// ---------------- per-row stats of masked r_mat: max, 1/sum(exp) ------------
__global__ void rowstats_kernel(const float* __restrict__ r_mat,
                                const float* __restrict__ attn,
                                const float* __restrict__ pad,
                                float* __restrict__ m1, float* __restrict__ is1) {
  int row = blockIdx.x * 4 + (threadIdx.x >> 6);
  int lane = threadIdx.x & 63;
  int b = row >> 11, q = row & 2047;
  const float* rrow = r_mat + (size_t)row * SS;
  const float* arow = attn + (size_t)q * SS;
  const float* prow = pad + (size_t)b * SS;
  float vals[32];
  float mx = -__builtin_inff();
#pragma unroll
  for (int i = 0; i < 8; ++i) {
    int c = i * 256 + lane * 4;
    float4 rv = *(const float4*)(rrow + c);
    float4 av = *(const float4*)(arow + c);
    float4 pv = *(const float4*)(prow + c);
    float v0 = (pv.x == 0.f || av.x == 0.f) ? NEGV : rv.x;
    float v1 = (pv.y == 0.f || av.y == 0.f) ? NEGV : rv.y;
    float v2 = (pv.z == 0.f || av.z == 0.f) ? NEGV : rv.z;
    float v3 = (pv.w == 0.f || av.w == 0.f) ? NEGV : rv.w;
    vals[i * 4 + 0] = v0; vals[i * 4 + 1] = v1;
    vals[i * 4 + 2] = v2; vals[i * 4 + 3] = v3;
    mx = fmaxf(mx, fmaxf(fmaxf(v0, v1), fmaxf(v2, v3)));
  }
#pragma unroll
  for (int m = 1; m < 64; m <<= 1) mx = fmaxf(mx, __shfl_xor(mx, m));
  float sum = 0.f;
#pragma unroll
  for (int i = 0; i < 32; ++i) sum += __expf(vals[i] - mx);
#pragma unroll
  for (int m = 1; m < 64; m <<= 1) sum += __shfl_xor(sum, m);
  if (lane == 0) { m1[row] = mx; is1[row] = 1.f / sum; }
}

// ---------------- flash attention, one wave = 16 q rows ---------------------
__global__ void flash_kernel(const unsigned short* __restrict__ hb,
                             const unsigned short* __restrict__ hbT,
                             const float* __restrict__ x,
                             const float* __restrict__ r_mat,
                             const float* __restrict__ attn,
                             const float* __restrict__ pad,
                             const float* __restrict__ m1,
                             const float* __restrict__ is1,
                             float* __restrict__ out) {
  __shared__ unsigned short ldsP[16][48];  // P bounce: C-layout -> A-layout
  int bid = blockIdx.x;
  int b = bid >> 7, qt = bid & 127;
  int q0 = qt * 16;
  int lane = threadIdx.x;
  int lr = lane & 15, lg = lane >> 4;

  const unsigned short* hbB = hb + (size_t)b * SS * DD;
  const unsigned short* hbTB = hbT + (size_t)b * DD * SS;
  const float* padB = pad + (size_t)b * SS;

  bf16x8 aq[8];
#pragma unroll
  for (int dc = 0; dc < 8; ++dc) {
    U16 u; u.u = *(const uint4*)(hbB + (size_t)(q0 + lr) * DD + dc * 32 + lg * 8);
    aq[dc] = u.b;
  }
  float m1v[4], is1v[4];
#pragma unroll
  for (int r = 0; r < 4; ++r) {
    int q = q0 + lg * 4 + r;
    m1v[r] = m1[(size_t)b * SS + q];
    is1v[r] = is1[(size_t)b * SS + q];
  }
  float mrun[4], lrun[4];
#pragma unroll
  for (int r = 0; r < 4; ++r) { mrun[r] = -__builtin_inff(); lrun[r] = 0.f; }
  f32x4 acc[16];
#pragma unroll
  for (int d = 0; d < 16; ++d) acc[d] = (f32x4){0.f, 0.f, 0.f, 0.f};

  for (int kt = 0; kt < 64; ++kt) {
    int k0 = kt * 32;
    f32x4 sa = (f32x4){0.f, 0.f, 0.f, 0.f};
    f32x4 sb = (f32x4){0.f, 0.f, 0.f, 0.f};
#pragma unroll
    for (int dc = 0; dc < 8; ++dc) {
      U16 u0; u0.u = *(const uint4*)(hbB + (size_t)(k0 + lr) * DD + dc * 32 + lg * 8);
      U16 u1; u1.u = *(const uint4*)(hbB + (size_t)(k0 + 16 + lr) * DD + dc * 32 + lg * 8);
      sa = __builtin_amdgcn_mfma_f32_16x16x32_bf16(aq[dc], u0.b, sa, 0, 0, 0);
      sb = __builtin_amdgcn_mfma_f32_16x16x32_bf16(aq[dc], u1.b, sb, 0, 0, 0);
    }
    float sc0[4], sc1[4];
    {
      int ka = k0 + lr, kb = k0 + 16 + lr;
      float pa_ = padB[ka], pb_ = padB[kb];
#pragma unroll
      for (int r = 0; r < 4; ++r) {
        int q = q0 + lg * 4 + r;
        float ra = r_mat[((size_t)b * SS + q) * SS + ka];
        float rb = r_mat[((size_t)b * SS + q) * SS + kb];
        float aa = attn[(size_t)q * SS + ka];
        float ab = attn[(size_t)q * SS + kb];
        float rma = (pa_ == 0.f || aa == 0.f) ? NEGV : ra;
        float rmb = (pb_ == 0.f || ab == 0.f) ? NEGV : rb;
        sc0[r] = sa[r] * 0.0625f + __expf(rma - m1v[r]) * is1v[r];
        sc1[r] = sb[r] * 0.0625f + __expf(rmb - m1v[r]) * is1v[r];
      }
    }
    float alpha[4];
#pragma unroll
    for (int r = 0; r < 4; ++r) {
      float tm = fmaxf(sc0[r], sc1[r]);
      tm = fmaxf(tm, __shfl_xor(tm, 1));
      tm = fmaxf(tm, __shfl_xor(tm, 2));
      tm = fmaxf(tm, __shfl_xor(tm, 4));
      tm = fmaxf(tm, __shfl_xor(tm, 8));
      float mnew = fmaxf(mrun[r], tm);
      float a = __expf(mrun[r] - mnew);
      float p0 = __expf(sc0[r] - mnew);
      float p1 = __expf(sc1[r] - mnew);
      float rs = p0 + p1;
      rs += __shfl_xor(rs, 1);
      rs += __shfl_xor(rs, 2);
      rs += __shfl_xor(rs, 4);
      rs += __shfl_xor(rs, 8);
      lrun[r] = lrun[r] * a + rs;
      mrun[r] = mnew;
      alpha[r] = a;
      ldsP[lg * 4 + r][lr] = tobf(p0);
      ldsP[lg * 4 + r][16 + lr] = tobf(p1);
    }
    __syncthreads();
#pragma unroll
    for (int d = 0; d < 16; ++d) {
      acc[d][0] *= alpha[0]; acc[d][1] *= alpha[1];
      acc[d][2] *= alpha[2]; acc[d][3] *= alpha[3];
    }
    U16 pafrag; pafrag.u = *(const uint4*)&ldsP[lr][lg * 8];
#pragma unroll
    for (int d = 0; d < 16; ++d) {
      U16 bv; bv.u = *(const uint4*)(hbTB + (size_t)(d * 16 + lr) * SS + k0 + lg * 8);
      acc[d] = __builtin_amdgcn_mfma_f32_16x16x32_bf16(pafrag.b, bv.b, acc[d], 0, 0, 0);
    }
    __syncthreads();
  }
#pragma unroll
  for (int r = 0; r < 4; ++r) {
    int q = q0 + lg * 4 + r;
    float inv = 1.f / lrun[r];
    const float* xr = x + ((size_t)b * SS + q) * DD;
    float* orow = out + ((size_t)b * SS + q) * DD;
#pragma unroll
    for (int d = 0; d < 16; ++d)
      orow[d * 16 + lr] = acc[d][r] * inv + xr[d * 16 + lr];
  }
}

// ---------------- weight transpose+convert: src[K][N] f32 -> dst[N][K] bf16 -
__global__ void wconv_kernel(const float* __restrict__ src, unsigned short* __restrict__ dst,
                             int K, int N) {
  int k = blockIdx.x;
  for (int n = threadIdx.x; n < N; n += 256)
    dst[(size_t)n * K + k] = tobf(src[(size_t)k * N + n]);
}

// ---------------- FFN1: [16384,256] @ [256,1024] + b1, relu -> bf16 ---------
__global__ void ffn1_kernel(const unsigned short* __restrict__ A,
                            const unsigned short* __restrict__ Bt,
                            const float* __restrict__ bias,
                            unsigned short* __restrict__ Out) {
  int bid = blockIdx.x;
  int nb = bid & 7, mb = bid >> 3;
  int wid = threadIdx.x >> 6, lane = threadIdx.x & 63;
  int wm = wid >> 1, wn = wid & 1;
  int lr = lane & 15, lg = lane >> 4;
  int m0 = mb * 128 + wm * 64;
  int n0 = nb * 128 + wn * 64;
  f32x4 acc[4][4];
#pragma unroll
  for (int i = 0; i < 4; ++i)
#pragma unroll
    for (int j = 0; j < 4; ++j) acc[i][j] = (f32x4){0.f, 0.f, 0.f, 0.f};
#pragma unroll
  for (int kc = 0; kc < 8; ++kc) {
    bf16x8 am[4], bn[4];
#pragma unroll
    for (int i = 0; i < 4; ++i) {
      U16 u; u.u = *(const uint4*)(A + (size_t)(m0 + i * 16 + lr) * 256 + kc * 32 + lg * 8);
      am[i] = u.b;
      U16 v; v.u = *(const uint4*)(Bt + (size_t)(n0 + i * 16 + lr) * 256 + kc * 32 + lg * 8);
      bn[i] = v.b;
    }
#pragma unroll
    for (int i = 0; i < 4; ++i)
#pragma unroll
      for (int j = 0; j < 4; ++j)
        acc[i][j] = __builtin_amdgcn_mfma_f32_16x16x32_bf16(am[i], bn[j], acc[i][j], 0, 0, 0);
  }
#pragma unroll
  for (int i = 0; i < 4; ++i)
#pragma unroll
    for (int j = 0; j < 4; ++j)
#pragma unroll
      for (int r = 0; r < 4; ++r) {
        int m = m0 + i * 16 + lg * 4 + r;
        int n = n0 + j * 16 + lr;
        float v = fmaxf(acc[i][j][r] + bias[n], 0.f);
        Out[(size_t)m * 1024 + n] = tobf(v);
      }
}

// ---------------- FFN2: [16384,1024] @ [1024,256] + b2 + residual (f32) -----
__global__ void ffn2_kernel(const unsigned short* __restrict__ A,
                            const unsigned short* __restrict__ Bt,
                            const float* __restrict__ bias,
                            float* __restrict__ Out) {
  int bid = blockIdx.x;
  int nb = bid & 1, mb = bid >> 1;
  int wid = threadIdx.x >> 6, lane = threadIdx.x & 63;
  int wm = wid >> 1, wn = wid & 1;
  int lr = lane & 15, lg = lane >> 4;
  int m0 = mb * 128 + wm * 64;
  int n0 = nb * 128 + wn * 64;
  f32x4 acc[4][4];
#pragma unroll
  for (int i = 0; i < 4; ++i)
#pragma unroll
    for (int j = 0; j < 4; ++j) acc[i][j] = (f32x4){0.f, 0.f, 0.f, 0.f};
  for (int kc = 0; kc < 32; ++kc) {
    bf16x8 am[4], bn[4];
#pragma unroll
    for (int i = 0; i < 4; ++i) {
      U16 u; u.u = *(const uint4*)(A + (size_t)(m0 + i * 16 + lr) * 1024 + kc * 32 + lg * 8);
      am[i] = u.b;
      U16 v; v.u = *(const uint4*)(Bt + (size_t)(n0 + i * 16 + lr) * 1024 + kc * 32 + lg * 8);
      bn[i] = v.b;
    }
#pragma unroll
    for (int i = 0; i < 4; ++i)
#pragma unroll
      for (int j = 0; j < 4; ++j)
        acc[i][j] = __builtin_amdgcn_mfma_f32_16x16x32_bf16(am[i], bn[j], acc[i][j], 0, 0, 0);
  }
#pragma unroll
  for (int i = 0; i < 4; ++i)
#pragma unroll
    for (int j = 0; j < 4; ++j)
#pragma unroll
      for (int r = 0; r < 4; ++r) {
        int m = m0 + i * 16 + lg * 4 + r;
        int n = n0 + j * 16 + lr;
        Out[(size_t)m * 256 + n] += acc[i][j][r] + bias[n];
      }
}

extern "C" void kernel_launch(void* const* d_in, const int* in_sizes, int n_in,
                              void* d_out, int out_size, void* d_ws, size_t ws_size,
                              hipStream_t stream) {
  const float* x     = (const float*)d_in[0];
  const float* r_mat = (const float*)d_in[1];
  const float* attn  = (const float*)d_in[2];
  const float* pad   = (const float*)d_in[3];
  const float* ln1w  = (const float*)d_in[4];
  const float* ln1b  = (const float*)d_in[5];
  const float* ln2w  = (const float*)d_in[6];
  const float* ln2b  = (const float*)d_in[7];
  const float* w1    = (const float*)d_in[8];
  const float* b1    = (const float*)d_in[9];
  const float* w2    = (const float*)d_in[10];
  const float* b2    = (const float*)d_in[11];
  float* out = (float*)d_out;

  uint8_t* ws = (uint8_t*)d_ws;
  unsigned short* hb   = (unsigned short*)(ws + 0);          // 8,388,608
  unsigned short* hbT  = (unsigned short*)(ws + 8388608);    // 8,388,608
  unsigned short* h2b  = (unsigned short*)(ws + 16777216);   // 8,388,608
  unsigned short* w1bT = (unsigned short*)(ws + 25165824);   // 524,288
  unsigned short* w2bT = (unsigned short*)(ws + 25690112);   // 524,288
  float* m1            = (float*)(ws + 26214400);            // 65,536
  float* is1           = (float*)(ws + 26279936);            // 65,536
  unsigned short* t    = (unsigned short*)(ws + 26345472);   // 33,554,432  (end ~60MB)

  hipLaunchKernelGGL(ln_kernel, dim3(4096), dim3(256), 0, stream, x, ln1w, ln1b, hb);
  hipLaunchKernelGGL(transpose_kernel, dim3(1024), dim3(256), 0, stream, hb, hbT);
  hipLaunchKernelGGL(rowstats_kernel, dim3(4096), dim3(256), 0, stream, r_mat, attn, pad, m1, is1);
  hipLaunchKernelGGL(flash_kernel, dim3(1024), dim3(64), 0, stream,
                     hb, hbT, x, r_mat, attn, pad, m1, is1, out);
  hipLaunchKernelGGL(ln_kernel, dim3(4096), dim3(256), 0, stream, out, ln2w, ln2b, h2b);
  hipLaunchKernelGGL(wconv_kernel, dim3(256), dim3(256), 0, stream, w1, w1bT, 256, 1024);
  hipLaunchKernelGGL(wconv_kernel, dim3(1024), dim3(256), 0, stream, w2, w2bT, 1024, 256);
  hipLaunchKernelGGL(ffn1_kernel, dim3(1024), dim3(256), 0, stream, h2b, w1bT, b1, t);
  hipLaunchKernelGGL(ffn2_kernel, dim3(256), dim3(256), 0, stream, t, w2bT, b2, out);
}

// Round 2
// 461.333 us; speedup vs baseline: 1.4952x; 1.4952x over previous
//
#include <hip/hip_runtime.h>
#include <stdint.h>

#define NB 8
#define SS 2048
#define DD 256
#define NEGV -1e9f

typedef __attribute__((ext_vector_type(8))) __bf16 bf16x8;
typedef __attribute__((ext_vector_type(4))) float f32x4;

union U16 { uint4 u; bf16x8 b; };

__device__ __forceinline__ unsigned short tobf(float v) {
  union { float f; uint32_t u; } c; c.f = v;
  uint32_t r = (c.u + 0x7fffu + ((c.u >> 16) & 1u)) >> 16;
  return (unsigned short)r;
}
__device__ __forceinline__ float frombf(unsigned short v) {
  union { uint32_t u; float f; } c; c.u = ((uint32_t)v) << 16;
  return c.f;
}

// ---------------- LayerNorm (f32 in -> bf16 out), one wave per row ----------
__global__ void ln_kernel(const float* __restrict__ in, const float* __restrict__ w,
                          const float* __restrict__ bparm, unsigned short* __restrict__ outb) {
  int row = blockIdx.x * 4 + (threadIdx.x >> 6);
  int lane = threadIdx.x & 63;
  const float* xr = in + (size_t)row * DD;
  float4 v = *(const float4*)(xr + lane * 4);
  float s = v.x + v.y + v.z + v.w;
  float s2 = v.x * v.x + v.y * v.y + v.z * v.z + v.w * v.w;
#pragma unroll
  for (int m = 1; m < 64; m <<= 1) { s += __shfl_xor(s, m); s2 += __shfl_xor(s2, m); }
  float mu = s * (1.f / DD);
  float var = s2 * (1.f / DD) - mu * mu;
  float rs = rsqrtf(var + 1e-5f);
  float4 wv = *(const float4*)(w + lane * 4);
  float4 bv = *(const float4*)(bparm + lane * 4);
  ushort4 o;
  o.x = tobf((v.x - mu) * rs * wv.x + bv.x);
  o.y = tobf((v.y - mu) * rs * wv.y + bv.y);
  o.z = tobf((v.z - mu) * rs * wv.z + bv.z);
  o.w = tobf((v.w - mu) * rs * wv.w + bv.w);
  *(ushort4*)(outb + (size_t)row * DD + lane * 4) = o;
}

// ---------------- bf16 [B,S,D] -> [B,D,S] transpose, 64x64 LDS tiles --------
__global__ void transpose_kernel(const unsigned short* __restrict__ in,
                                 unsigned short* __restrict__ out) {
  __shared__ unsigned short tile[64][72];
  int bid = blockIdx.x;
  int b = bid >> 7;
  int rest = bid & 127;
  int st = rest >> 2, dt = rest & 3;
  int s0 = st * 64, d0 = dt * 64;
  int t = threadIdx.x;
  int r = t >> 2, cs = (t & 3) * 16;
  const unsigned short* src = in + ((size_t)b * SS + s0 + r) * DD + d0 + cs;
  *(uint4*)&tile[r][cs] = *(const uint4*)src;
  *(uint4*)&tile[r][cs + 8] = *(const uint4*)(src + 8);
  __syncthreads();
  union { unsigned short us[16]; uint4 u[2]; } tmp;
  int dr = t >> 2, sseg = (t & 3) * 16;
#pragma unroll
  for (int j = 0; j < 16; ++j) tmp.us[j] = tile[sseg + j][dr];
  unsigned short* dst = out + ((size_t)b * DD + d0 + dr) * SS + s0 + sseg;
  *(uint4*)dst = tmp.u[0];
  *(uint4*)(dst + 8) = tmp.u[1];
}

// ---------------- per-row stats of masked r_mat: max, 1/sum(exp) ------------
__global__ void rowstats_kernel(const float* __restrict__ r_mat,
                                const float* __restrict__ attn,
                                const float* __restrict__ pad,
                                float* __restrict__ m1, float* __restrict__ is1) {
  int row = blockIdx.x * 4 + (threadIdx.x >> 6);
  int lane = threadIdx.x & 63;
  int b = row >> 11, q = row & 2047;
  const float* rrow = r_mat + (size_t)row * SS;
  const float* arow = attn + (size_t)q * SS;
  const float* prow = pad + (size_t)b * SS;
  float vals[32];
  float mx = -__builtin_inff();
#pragma unroll
  for (int i = 0; i < 8; ++i) {
    int c = i * 256 + lane * 4;
    float4 rv = *(const float4*)(rrow + c);
    float4 av = *(const float4*)(arow + c);
    float4 pv = *(const float4*)(prow + c);
    float v0 = (pv.x == 0.f || av.x == 0.f) ? NEGV : rv.x;
    float v1 = (pv.y == 0.f || av.y == 0.f) ? NEGV : rv.y;
    float v2 = (pv.z == 0.f || av.z == 0.f) ? NEGV : rv.z;
    float v3 = (pv.w == 0.f || av.w == 0.f) ? NEGV : rv.w;
    vals[i * 4 + 0] = v0; vals[i * 4 + 1] = v1;
    vals[i * 4 + 2] = v2; vals[i * 4 + 3] = v3;
    mx = fmaxf(mx, fmaxf(fmaxf(v0, v1), fmaxf(v2, v3)));
  }
#pragma unroll
  for (int m = 1; m < 64; m <<= 1) mx = fmaxf(mx, __shfl_xor(mx, m));
  float sum = 0.f;
#pragma unroll
  for (int i = 0; i < 32; ++i) sum += __expf(vals[i] - mx);
#pragma unroll
  for (int m = 1; m < 64; m <<= 1) sum += __shfl_xor(sum, m);
  if (lane == 0) { m1[row] = mx; is1[row] = 1.f / sum; }
}

// ---------------- flash attention, split-K: 8 waves/block, LDS merge --------
// block = 512 threads = 8 waves; wave w handles k in [w*256, (w+1)*256)
// for one 16-row q tile. Partial (m,l,O) merged through bf16 LDS.
__global__ __launch_bounds__(512) void flash_kernel(
    const unsigned short* __restrict__ hb,
    const unsigned short* __restrict__ hbT,
    const float* __restrict__ x,
    const float* __restrict__ r_mat,
    const float* __restrict__ attn,
    const float* __restrict__ pad,
    const float* __restrict__ m1,
    const float* __restrict__ is1,
    float* __restrict__ out) {
  __shared__ __align__(16) unsigned short Obuf[8][16][264];  // bf16 partials (+pad)
  __shared__ float Mbuf[8][16];
  __shared__ float Lbuf[8][16];

  int bid = blockIdx.x;
  int b = bid >> 7, qt = bid & 127;
  int q0 = qt * 16;
  int w = threadIdx.x >> 6;
  int lane = threadIdx.x & 63;
  int lr = lane & 15, lg = lane >> 4;

  const unsigned short* hbB = hb + (size_t)b * SS * DD;
  const unsigned short* hbTB = hbT + (size_t)b * DD * SS;
  const float* padB = pad + (size_t)b * SS;

  // per-wave P bounce lives inside this wave's Obuf slice (reused later)
  unsigned short (*ldsP)[48] = (unsigned short (*)[48])&Obuf[w][0][0];

  bf16x8 aq[8];
#pragma unroll
  for (int dc = 0; dc < 8; ++dc) {
    U16 u; u.u = *(const uint4*)(hbB + (size_t)(q0 + lr) * DD + dc * 32 + lg * 8);
    aq[dc] = u.b;
  }
  float m1v[4], is1v[4];
#pragma unroll
  for (int r = 0; r < 4; ++r) {
    int q = q0 + lg * 4 + r;
    m1v[r] = m1[(size_t)b * SS + q];
    is1v[r] = is1[(size_t)b * SS + q];
  }
  float mrun[4], lrun[4];
#pragma unroll
  for (int r = 0; r < 4; ++r) { mrun[r] = -__builtin_inff(); lrun[r] = 0.f; }
  f32x4 acc[16];
#pragma unroll
  for (int d = 0; d < 16; ++d) acc[d] = (f32x4){0.f, 0.f, 0.f, 0.f};

  for (int kt = w * 8; kt < w * 8 + 8; ++kt) {
    int k0 = kt * 32;
    f32x4 sa = (f32x4){0.f, 0.f, 0.f, 0.f};
    f32x4 sb = (f32x4){0.f, 0.f, 0.f, 0.f};
#pragma unroll
    for (int dc = 0; dc < 8; ++dc) {
      U16 u0; u0.u = *(const uint4*)(hbB + (size_t)(k0 + lr) * DD + dc * 32 + lg * 8);
      U16 u1; u1.u = *(const uint4*)(hbB + (size_t)(k0 + 16 + lr) * DD + dc * 32 + lg * 8);
      sa = __builtin_amdgcn_mfma_f32_16x16x32_bf16(aq[dc], u0.b, sa, 0, 0, 0);
      sb = __builtin_amdgcn_mfma_f32_16x16x32_bf16(aq[dc], u1.b, sb, 0, 0, 0);
    }
    float sc0[4], sc1[4];
    {
      int ka = k0 + lr, kb = k0 + 16 + lr;
      float pa_ = padB[ka], pb_ = padB[kb];
#pragma unroll
      for (int r = 0; r < 4; ++r) {
        int q = q0 + lg * 4 + r;
        float ra = r_mat[((size_t)b * SS + q) * SS + ka];
        float rb = r_mat[((size_t)b * SS + q) * SS + kb];
        float aa = attn[(size_t)q * SS + ka];
        float ab = attn[(size_t)q * SS + kb];
        float rma = (pa_ == 0.f || aa == 0.f) ? NEGV : ra;
        float rmb = (pb_ == 0.f || ab == 0.f) ? NEGV : rb;
        sc0[r] = sa[r] * 0.0625f + __expf(rma - m1v[r]) * is1v[r];
        sc1[r] = sb[r] * 0.0625f + __expf(rmb - m1v[r]) * is1v[r];
      }
    }
    float alpha[4];
#pragma unroll
    for (int r = 0; r < 4; ++r) {
      float tm = fmaxf(sc0[r], sc1[r]);
      tm = fmaxf(tm, __shfl_xor(tm, 1));
      tm = fmaxf(tm, __shfl_xor(tm, 2));
      tm = fmaxf(tm, __shfl_xor(tm, 4));
      tm = fmaxf(tm, __shfl_xor(tm, 8));
      float mnew = fmaxf(mrun[r], tm);
      float a = __expf(mrun[r] - mnew);
      float p0 = __expf(sc0[r] - mnew);
      float p1 = __expf(sc1[r] - mnew);
      float rs = p0 + p1;
      rs += __shfl_xor(rs, 1);
      rs += __shfl_xor(rs, 2);
      rs += __shfl_xor(rs, 4);
      rs += __shfl_xor(rs, 8);
      lrun[r] = lrun[r] * a + rs;
      mrun[r] = mnew;
      alpha[r] = a;
      ldsP[lg * 4 + r][lr] = tobf(p0);
      ldsP[lg * 4 + r][16 + lr] = tobf(p1);
    }
    // intra-wave fence: P writes must land before cross-lane P reads
    asm volatile("s_waitcnt lgkmcnt(0)" ::: "memory");
    __builtin_amdgcn_sched_barrier(0);
#pragma unroll
    for (int d = 0; d < 16; ++d) {
      acc[d][0] *= alpha[0]; acc[d][1] *= alpha[1];
      acc[d][2] *= alpha[2]; acc[d][3] *= alpha[3];
    }
    U16 pafrag; pafrag.u = *(const uint4*)&ldsP[lr][lg * 8];
#pragma unroll
    for (int d = 0; d < 16; ++d) {
      U16 bv; bv.u = *(const uint4*)(hbTB + (size_t)(d * 16 + lr) * SS + k0 + lg * 8);
      acc[d] = __builtin_amdgcn_mfma_f32_16x16x32_bf16(pafrag.b, bv.b, acc[d], 0, 0, 0);
    }
    // reads done before next iteration's P writes (in-order LDS per wave +
    // compiler waits on pafrag use); writes of next iter follow program order
    asm volatile("s_waitcnt lgkmcnt(0)" ::: "memory");
  }

  // ---- write partial state to LDS ----
#pragma unroll
  for (int d = 0; d < 16; ++d)
#pragma unroll
    for (int r = 0; r < 4; ++r)
      Obuf[w][lg * 4 + r][d * 16 + lr] = tobf(acc[d][r]);
  if (lr == 0) {
#pragma unroll
    for (int r = 0; r < 4; ++r) {
      Mbuf[w][lg * 4 + r] = mrun[r];
      Lbuf[w][lg * 4 + r] = lrun[r];
    }
  }
  __syncthreads();

  // ---- merge 8 partials: 512 threads over 16 rows x 256 cols ----
  int t = threadIdx.x;
  int row = t >> 5, cb = (t & 31) * 8;
  float mv[8];
  float mstar = -__builtin_inff();
#pragma unroll
  for (int w2 = 0; w2 < 8; ++w2) { mv[w2] = Mbuf[w2][row]; mstar = fmaxf(mstar, mv[w2]); }
  float wgt[8];
  float L = 0.f;
#pragma unroll
  for (int w2 = 0; w2 < 8; ++w2) {
    wgt[w2] = __expf(mv[w2] - mstar);
    L += wgt[w2] * Lbuf[w2][row];
  }
  float o[8];
#pragma unroll
  for (int j = 0; j < 8; ++j) o[j] = 0.f;
#pragma unroll
  for (int w2 = 0; w2 < 8; ++w2) {
    union { uint4 u; unsigned short us[8]; } pk;
    pk.u = *(const uint4*)&Obuf[w2][row][cb];
#pragma unroll
    for (int j = 0; j < 8; ++j) o[j] += wgt[w2] * frombf(pk.us[j]);
  }
  float invL = 1.f / L;
  const float* xr = x + ((size_t)b * SS + q0 + row) * DD + cb;
  float* orow = out + ((size_t)b * SS + q0 + row) * DD + cb;
  float4 x0 = *(const float4*)xr;
  float4 x1 = *(const float4*)(xr + 4);
  float4 r0, r1;
  r0.x = o[0] * invL + x0.x; r0.y = o[1] * invL + x0.y;
  r0.z = o[2] * invL + x0.z; r0.w = o[3] * invL + x0.w;
  r1.x = o[4] * invL + x1.x; r1.y = o[5] * invL + x1.y;
  r1.z = o[6] * invL + x1.z; r1.w = o[7] * invL + x1.w;
  *(float4*)orow = r0;
  *(float4*)(orow + 4) = r1;
}

// ---------------- weight transpose+convert: src[K][N] f32 -> dst[N][K] bf16 -
__global__ void wconv_kernel(const float* __restrict__ src, unsigned short* __restrict__ dst,
                             int K, int N) {
  int k = blockIdx.x;
  for (int n = threadIdx.x; n < N; n += 256)
    dst[(size_t)n * K + k] = tobf(src[(size_t)k * N + n]);
}

// ---------------- FFN1: [16384,256] @ [256,1024] + b1, relu -> bf16 ---------
__global__ void ffn1_kernel(const unsigned short* __restrict__ A,
                            const unsigned short* __restrict__ Bt,
                            const float* __restrict__ bias,
                            unsigned short* __restrict__ Out) {
  int bid = blockIdx.x;
  int nb = bid & 7, mb = bid >> 3;
  int wid = threadIdx.x >> 6, lane = threadIdx.x & 63;
  int wm = wid >> 1, wn = wid & 1;
  int lr = lane & 15, lg = lane >> 4;
  int m0 = mb * 128 + wm * 64;
  int n0 = nb * 128 + wn * 64;
  f32x4 acc[4][4];
#pragma unroll
  for (int i = 0; i < 4; ++i)
#pragma unroll
    for (int j = 0; j < 4; ++j) acc[i][j] = (f32x4){0.f, 0.f, 0.f, 0.f};
#pragma unroll
  for (int kc = 0; kc < 8; ++kc) {
    bf16x8 am[4], bn[4];
#pragma unroll
    for (int i = 0; i < 4; ++i) {
      U16 u; u.u = *(const uint4*)(A + (size_t)(m0 + i * 16 + lr) * 256 + kc * 32 + lg * 8);
      am[i] = u.b;
      U16 v; v.u = *(const uint4*)(Bt + (size_t)(n0 + i * 16 + lr) * 256 + kc * 32 + lg * 8);
      bn[i] = v.b;
    }
#pragma unroll
    for (int i = 0; i < 4; ++i)
#pragma unroll
      for (int j = 0; j < 4; ++j)
        acc[i][j] = __builtin_amdgcn_mfma_f32_16x16x32_bf16(am[i], bn[j], acc[i][j], 0, 0, 0);
  }
#pragma unroll
  for (int i = 0; i < 4; ++i)
#pragma unroll
    for (int j = 0; j < 4; ++j)
#pragma unroll
      for (int r = 0; r < 4; ++r) {
        int m = m0 + i * 16 + lg * 4 + r;
        int n = n0 + j * 16 + lr;
        float v = fmaxf(acc[i][j][r] + bias[n], 0.f);
        Out[(size_t)m * 1024 + n] = tobf(v);
      }
}

// ---------------- FFN2: [16384,1024] @ [1024,256] + b2 + residual (f32) -----
__global__ void ffn2_kernel(const unsigned short* __restrict__ A,
                            const unsigned short* __restrict__ Bt,
                            const float* __restrict__ bias,
                            float* __restrict__ Out) {
  int bid = blockIdx.x;
  int nb = bid & 1, mb = bid >> 1;
  int wid = threadIdx.x >> 6, lane = threadIdx.x & 63;
  int wm = wid >> 1, wn = wid & 1;
  int lr = lane & 15, lg = lane >> 4;
  int m0 = mb * 128 + wm * 64;
  int n0 = nb * 128 + wn * 64;
  f32x4 acc[4][4];
#pragma unroll
  for (int i = 0; i < 4; ++i)
#pragma unroll
    for (int j = 0; j < 4; ++j) acc[i][j] = (f32x4){0.f, 0.f, 0.f, 0.f};
  for (int kc = 0; kc < 32; ++kc) {
    bf16x8 am[4], bn[4];
#pragma unroll
    for (int i = 0; i < 4; ++i) {
      U16 u; u.u = *(const uint4*)(A + (size_t)(m0 + i * 16 + lr) * 1024 + kc * 32 + lg * 8);
      am[i] = u.b;
      U16 v; v.u = *(const uint4*)(Bt + (size_t)(n0 + i * 16 + lr) * 1024 + kc * 32 + lg * 8);
      bn[i] = v.b;
    }
#pragma unroll
    for (int i = 0; i < 4; ++i)
#pragma unroll
      for (int j = 0; j < 4; ++j)
        acc[i][j] = __builtin_amdgcn_mfma_f32_16x16x32_bf16(am[i], bn[j], acc[i][j], 0, 0, 0);
  }
#pragma unroll
  for (int i = 0; i < 4; ++i)
#pragma unroll
    for (int j = 0; j < 4; ++j)
#pragma unroll
      for (int r = 0; r < 4; ++r) {
        int m = m0 + i * 16 + lg * 4 + r;
        int n = n0 + j * 16 + lr;
        Out[(size_t)m * 256 + n] += acc[i][j][r] + bias[n];
      }
}

extern "C" void kernel_launch(void* const* d_in, const int* in_sizes, int n_in,
                              void* d_out, int out_size, void* d_ws, size_t ws_size,
                              hipStream_t stream) {
  const float* x     = (const float*)d_in[0];
  const float* r_mat = (const float*)d_in[1];
  const float* attn  = (const float*)d_in[2];
  const float* pad   = (const float*)d_in[3];
  const float* ln1w  = (const float*)d_in[4];
  const float* ln1b  = (const float*)d_in[5];
  const float* ln2w  = (const float*)d_in[6];
  const float* ln2b  = (const float*)d_in[7];
  const float* w1    = (const float*)d_in[8];
  const float* b1    = (const float*)d_in[9];
  const float* w2    = (const float*)d_in[10];
  const float* b2    = (const float*)d_in[11];
  float* out = (float*)d_out;

  uint8_t* ws = (uint8_t*)d_ws;
  unsigned short* hb   = (unsigned short*)(ws + 0);          // 8,388,608
  unsigned short* hbT  = (unsigned short*)(ws + 8388608);    // 8,388,608
  unsigned short* h2b  = (unsigned short*)(ws + 16777216);   // 8,388,608
  unsigned short* w1bT = (unsigned short*)(ws + 25165824);   // 524,288
  unsigned short* w2bT = (unsigned short*)(ws + 25690112);   // 524,288
  float* m1            = (float*)(ws + 26214400);            // 65,536
  float* is1           = (float*)(ws + 26279936);            // 65,536
  unsigned short* t    = (unsigned short*)(ws + 26345472);   // 33,554,432

  hipLaunchKernelGGL(ln_kernel, dim3(4096), dim3(256), 0, stream, x, ln1w, ln1b, hb);
  hipLaunchKernelGGL(transpose_kernel, dim3(1024), dim3(256), 0, stream, hb, hbT);
  hipLaunchKernelGGL(rowstats_kernel, dim3(4096), dim3(256), 0, stream, r_mat, attn, pad, m1, is1);
  hipLaunchKernelGGL(flash_kernel, dim3(1024), dim3(512), 0, stream,
                     hb, hbT, x, r_mat, attn, pad, m1, is1, out);
  hipLaunchKernelGGL(ln_kernel, dim3(4096), dim3(256), 0, stream, out, ln2w, ln2b, h2b);
  hipLaunchKernelGGL(wconv_kernel, dim3(256), dim3(256), 0, stream, w1, w1bT, 256, 1024);
  hipLaunchKernelGGL(wconv_kernel, dim3(1024), dim3(256), 0, stream, w2, w2bT, 1024, 256);
  hipLaunchKernelGGL(ffn1_kernel, dim3(1024), dim3(256), 0, stream, h2b, w1bT, b1, t);
  hipLaunchKernelGGL(ffn2_kernel, dim3(256), dim3(256), 0, stream, t, w2bT, b2, out);
}

// Round 3
// 456.613 us; speedup vs baseline: 1.5107x; 1.0103x over previous
//
#include <hip/hip_runtime.h>
#include <stdint.h>

#define NB 8
#define SS 2048
#define DD 256
#define NEGV -1e9f

typedef __attribute__((ext_vector_type(8))) __bf16 bf16x8;
typedef __attribute__((ext_vector_type(4))) float f32x4;

union U16 { uint4 u; bf16x8 b; };

__device__ __forceinline__ unsigned short tobf(float v) {
  union { float f; uint32_t u; } c; c.f = v;
  uint32_t r = (c.u + 0x7fffu + ((c.u >> 16) & 1u)) >> 16;
  return (unsigned short)r;
}
__device__ __forceinline__ float frombf(unsigned short v) {
  union { uint32_t u; float f; } c; c.u = ((uint32_t)v) << 16;
  return c.f;
}

// ---------------- LayerNorm (f32 in -> bf16 out), one wave per row ----------
__global__ void ln_kernel(const float* __restrict__ in, const float* __restrict__ w,
                          const float* __restrict__ bparm, unsigned short* __restrict__ outb) {
  int row = blockIdx.x * 4 + (threadIdx.x >> 6);
  int lane = threadIdx.x & 63;
  const float* xr = in + (size_t)row * DD;
  float4 v = *(const float4*)(xr + lane * 4);
  float s = v.x + v.y + v.z + v.w;
  float s2 = v.x * v.x + v.y * v.y + v.z * v.z + v.w * v.w;
#pragma unroll
  for (int m = 1; m < 64; m <<= 1) { s += __shfl_xor(s, m); s2 += __shfl_xor(s2, m); }
  float mu = s * (1.f / DD);
  float var = s2 * (1.f / DD) - mu * mu;
  float rs = rsqrtf(var + 1e-5f);
  float4 wv = *(const float4*)(w + lane * 4);
  float4 bv = *(const float4*)(bparm + lane * 4);
  ushort4 o;
  o.x = tobf((v.x - mu) * rs * wv.x + bv.x);
  o.y = tobf((v.y - mu) * rs * wv.y + bv.y);
  o.z = tobf((v.z - mu) * rs * wv.z + bv.z);
  o.w = tobf((v.w - mu) * rs * wv.w + bv.w);
  *(ushort4*)(outb + (size_t)row * DD + lane * 4) = o;
}

// ---------------- bf16 [B,S,D] -> [B,D,S] transpose, 64x64 LDS tiles --------
__global__ void transpose_kernel(const unsigned short* __restrict__ in,
                                 unsigned short* __restrict__ out) {
  __shared__ unsigned short tile[64][72];
  int bid = blockIdx.x;
  int b = bid >> 7;
  int rest = bid & 127;
  int st = rest >> 2, dt = rest & 3;
  int s0 = st * 64, d0 = dt * 64;
  int t = threadIdx.x;
  int r = t >> 2, cs = (t & 3) * 16;
  const unsigned short* src = in + ((size_t)b * SS + s0 + r) * DD + d0 + cs;
  *(uint4*)&tile[r][cs] = *(const uint4*)src;
  *(uint4*)&tile[r][cs + 8] = *(const uint4*)(src + 8);
  __syncthreads();
  union { unsigned short us[16]; uint4 u[2]; } tmp;
  int dr = t >> 2, sseg = (t & 3) * 16;
#pragma unroll
  for (int j = 0; j < 16; ++j) tmp.us[j] = tile[sseg + j][dr];
  unsigned short* dst = out + ((size_t)b * DD + d0 + dr) * SS + s0 + sseg;
  *(uint4*)dst = tmp.u[0];
  *(uint4*)(dst + 8) = tmp.u[1];
}

// ---------------- per-row stats of masked r_mat: max, 1/sum(exp) ------------
__global__ void rowstats_kernel(const float* __restrict__ r_mat,
                                const float* __restrict__ attn,
                                const float* __restrict__ pad,
                                float* __restrict__ m1, float* __restrict__ is1) {
  int row = blockIdx.x * 4 + (threadIdx.x >> 6);
  int lane = threadIdx.x & 63;
  int b = row >> 11, q = row & 2047;
  const float* rrow = r_mat + (size_t)row * SS;
  const float* arow = attn + (size_t)q * SS;
  const float* prow = pad + (size_t)b * SS;
  float vals[32];
  float mx = -__builtin_inff();
#pragma unroll
  for (int i = 0; i < 8; ++i) {
    int c = i * 256 + lane * 4;
    float4 rv = *(const float4*)(rrow + c);
    float4 av = *(const float4*)(arow + c);
    float4 pv = *(const float4*)(prow + c);
    float v0 = (pv.x == 0.f || av.x == 0.f) ? NEGV : rv.x;
    float v1 = (pv.y == 0.f || av.y == 0.f) ? NEGV : rv.y;
    float v2 = (pv.z == 0.f || av.z == 0.f) ? NEGV : rv.z;
    float v3 = (pv.w == 0.f || av.w == 0.f) ? NEGV : rv.w;
    vals[i * 4 + 0] = v0; vals[i * 4 + 1] = v1;
    vals[i * 4 + 2] = v2; vals[i * 4 + 3] = v3;
    mx = fmaxf(mx, fmaxf(fmaxf(v0, v1), fmaxf(v2, v3)));
  }
#pragma unroll
  for (int m = 1; m < 64; m <<= 1) mx = fmaxf(mx, __shfl_xor(mx, m));
  float sum = 0.f;
#pragma unroll
  for (int i = 0; i < 32; ++i) sum += __expf(vals[i] - mx);
#pragma unroll
  for (int m = 1; m < 64; m <<= 1) sum += __shfl_xor(sum, m);
  if (lane == 0) { m1[row] = mx; is1[row] = 1.f / sum; }
}

// ---------------- flash attention, split-K: 8 waves/block, LDS merge --------
// XCD-locality decode: b = bid&7 -> all blocks of batch b land on XCD b,
// so K/V (hb+hbT slice, 2MB) stay resident in that XCD's 4MB L2.
// Merge phase also computes LN2 in-register and emits h2b.
__global__ __launch_bounds__(512) void flash_kernel(
    const unsigned short* __restrict__ hb,
    const unsigned short* __restrict__ hbT,
    const float* __restrict__ x,
    const float* __restrict__ r_mat,
    const float* __restrict__ attn,
    const float* __restrict__ pad,
    const float* __restrict__ m1,
    const float* __restrict__ is1,
    const float* __restrict__ ln2w,
    const float* __restrict__ ln2b,
    float* __restrict__ out,
    unsigned short* __restrict__ h2b) {
  __shared__ __align__(16) unsigned short Obuf[8][16][264];  // bf16 partials (+pad)
  __shared__ float Mbuf[8][16];
  __shared__ float Lbuf[8][16];

  int bid = blockIdx.x;
  int b = bid & 7, qt = bid >> 3;     // XCD-aligned decode
  int q0 = qt * 16;
  int w = threadIdx.x >> 6;
  int lane = threadIdx.x & 63;
  int lr = lane & 15, lg = lane >> 4;

  const unsigned short* hbB = hb + (size_t)b * SS * DD;
  const unsigned short* hbTB = hbT + (size_t)b * DD * SS;
  const float* padB = pad + (size_t)b * SS;

  unsigned short (*ldsP)[48] = (unsigned short (*)[48])&Obuf[w][0][0];

  bf16x8 aq[8];
#pragma unroll
  for (int dc = 0; dc < 8; ++dc) {
    U16 u; u.u = *(const uint4*)(hbB + (size_t)(q0 + lr) * DD + dc * 32 + lg * 8);
    aq[dc] = u.b;
  }
  float m1v[4], is1v[4];
#pragma unroll
  for (int r = 0; r < 4; ++r) {
    int q = q0 + lg * 4 + r;
    m1v[r] = m1[(size_t)b * SS + q];
    is1v[r] = is1[(size_t)b * SS + q];
  }
  float mrun[4], lrun[4];
#pragma unroll
  for (int r = 0; r < 4; ++r) { mrun[r] = -__builtin_inff(); lrun[r] = 0.f; }
  f32x4 acc[16];
#pragma unroll
  for (int d = 0; d < 16; ++d) acc[d] = (f32x4){0.f, 0.f, 0.f, 0.f};

  for (int kt = w * 8; kt < w * 8 + 8; ++kt) {
    int k0 = kt * 32;
    f32x4 sa = (f32x4){0.f, 0.f, 0.f, 0.f};
    f32x4 sb = (f32x4){0.f, 0.f, 0.f, 0.f};
#pragma unroll
    for (int dc = 0; dc < 8; ++dc) {
      U16 u0; u0.u = *(const uint4*)(hbB + (size_t)(k0 + lr) * DD + dc * 32 + lg * 8);
      U16 u1; u1.u = *(const uint4*)(hbB + (size_t)(k0 + 16 + lr) * DD + dc * 32 + lg * 8);
      sa = __builtin_amdgcn_mfma_f32_16x16x32_bf16(aq[dc], u0.b, sa, 0, 0, 0);
      sb = __builtin_amdgcn_mfma_f32_16x16x32_bf16(aq[dc], u1.b, sb, 0, 0, 0);
    }
    float sc0[4], sc1[4];
    {
      int ka = k0 + lr, kb = k0 + 16 + lr;
      float pa_ = padB[ka], pb_ = padB[kb];
#pragma unroll
      for (int r = 0; r < 4; ++r) {
        int q = q0 + lg * 4 + r;
        float ra = r_mat[((size_t)b * SS + q) * SS + ka];
        float rb = r_mat[((size_t)b * SS + q) * SS + kb];
        float aa = attn[(size_t)q * SS + ka];
        float ab = attn[(size_t)q * SS + kb];
        float rma = (pa_ == 0.f || aa == 0.f) ? NEGV : ra;
        float rmb = (pb_ == 0.f || ab == 0.f) ? NEGV : rb;
        sc0[r] = sa[r] * 0.0625f + __expf(rma - m1v[r]) * is1v[r];
        sc1[r] = sb[r] * 0.0625f + __expf(rmb - m1v[r]) * is1v[r];
      }
    }
    float alpha[4];
#pragma unroll
    for (int r = 0; r < 4; ++r) {
      float tm = fmaxf(sc0[r], sc1[r]);
      tm = fmaxf(tm, __shfl_xor(tm, 1));
      tm = fmaxf(tm, __shfl_xor(tm, 2));
      tm = fmaxf(tm, __shfl_xor(tm, 4));
      tm = fmaxf(tm, __shfl_xor(tm, 8));
      float mnew = fmaxf(mrun[r], tm);
      float a = __expf(mrun[r] - mnew);
      float p0 = __expf(sc0[r] - mnew);
      float p1 = __expf(sc1[r] - mnew);
      float rs = p0 + p1;
      rs += __shfl_xor(rs, 1);
      rs += __shfl_xor(rs, 2);
      rs += __shfl_xor(rs, 4);
      rs += __shfl_xor(rs, 8);
      lrun[r] = lrun[r] * a + rs;
      mrun[r] = mnew;
      alpha[r] = a;
      ldsP[lg * 4 + r][lr] = tobf(p0);
      ldsP[lg * 4 + r][16 + lr] = tobf(p1);
    }
    asm volatile("s_waitcnt lgkmcnt(0)" ::: "memory");
    __builtin_amdgcn_sched_barrier(0);
#pragma unroll
    for (int d = 0; d < 16; ++d) {
      acc[d][0] *= alpha[0]; acc[d][1] *= alpha[1];
      acc[d][2] *= alpha[2]; acc[d][3] *= alpha[3];
    }
    U16 pafrag; pafrag.u = *(const uint4*)&ldsP[lr][lg * 8];
#pragma unroll
    for (int d = 0; d < 16; ++d) {
      U16 bv; bv.u = *(const uint4*)(hbTB + (size_t)(d * 16 + lr) * SS + k0 + lg * 8);
      acc[d] = __builtin_amdgcn_mfma_f32_16x16x32_bf16(pafrag.b, bv.b, acc[d], 0, 0, 0);
    }
    asm volatile("s_waitcnt lgkmcnt(0)" ::: "memory");
  }

  // ---- write partial state to LDS ----
#pragma unroll
  for (int d = 0; d < 16; ++d)
#pragma unroll
    for (int r = 0; r < 4; ++r)
      Obuf[w][lg * 4 + r][d * 16 + lr] = tobf(acc[d][r]);
  if (lr == 0) {
#pragma unroll
    for (int r = 0; r < 4; ++r) {
      Mbuf[w][lg * 4 + r] = mrun[r];
      Lbuf[w][lg * 4 + r] = lrun[r];
    }
  }
  __syncthreads();

  // ---- merge 8 partials: 512 threads over 16 rows x 256 cols; fused LN2 ----
  int t = threadIdx.x;
  int row = t >> 5, cb = (t & 31) * 8;
  float mv[8];
  float mstar = -__builtin_inff();
#pragma unroll
  for (int w2 = 0; w2 < 8; ++w2) { mv[w2] = Mbuf[w2][row]; mstar = fmaxf(mstar, mv[w2]); }
  float wgt[8];
  float L = 0.f;
#pragma unroll
  for (int w2 = 0; w2 < 8; ++w2) {
    wgt[w2] = __expf(mv[w2] - mstar);
    L += wgt[w2] * Lbuf[w2][row];
  }
  float o[8];
#pragma unroll
  for (int j = 0; j < 8; ++j) o[j] = 0.f;
#pragma unroll
  for (int w2 = 0; w2 < 8; ++w2) {
    union { uint4 u; unsigned short us[8]; } pk;
    pk.u = *(const uint4*)&Obuf[w2][row][cb];
#pragma unroll
    for (int j = 0; j < 8; ++j) o[j] += wgt[w2] * frombf(pk.us[j]);
  }
  float invL = 1.f / L;
  const float* xr = x + ((size_t)b * SS + q0 + row) * DD + cb;
  float* orow = out + ((size_t)b * SS + q0 + row) * DD + cb;
  float4 x0 = *(const float4*)xr;
  float4 x1 = *(const float4*)(xr + 4);
  float val[8];
  val[0] = o[0] * invL + x0.x; val[1] = o[1] * invL + x0.y;
  val[2] = o[2] * invL + x0.z; val[3] = o[3] * invL + x0.w;
  val[4] = o[4] * invL + x1.x; val[5] = o[5] * invL + x1.y;
  val[6] = o[6] * invL + x1.z; val[7] = o[7] * invL + x1.w;
  float4 r0 = {val[0], val[1], val[2], val[3]};
  float4 r1 = {val[4], val[5], val[6], val[7]};
  *(float4*)orow = r0;
  *(float4*)(orow + 4) = r1;

  // fused LN2 over the 32 threads (half-wave) holding this row
  float s = 0.f, s2 = 0.f;
#pragma unroll
  for (int j = 0; j < 8; ++j) { s += val[j]; s2 += val[j] * val[j]; }
#pragma unroll
  for (int m = 1; m < 32; m <<= 1) { s += __shfl_xor(s, m); s2 += __shfl_xor(s2, m); }
  float mu = s * (1.f / DD);
  float var = s2 * (1.f / DD) - mu * mu;
  float rsv = rsqrtf(var + 1e-5f);
  float4 w0 = *(const float4*)(ln2w + cb);
  float4 w1 = *(const float4*)(ln2w + cb + 4);
  float4 bb0 = *(const float4*)(ln2b + cb);
  float4 bb1 = *(const float4*)(ln2b + cb + 4);
  ushort4 h0, h1;
  h0.x = tobf((val[0] - mu) * rsv * w0.x + bb0.x);
  h0.y = tobf((val[1] - mu) * rsv * w0.y + bb0.y);
  h0.z = tobf((val[2] - mu) * rsv * w0.z + bb0.z);
  h0.w = tobf((val[3] - mu) * rsv * w0.w + bb0.w);
  h1.x = tobf((val[4] - mu) * rsv * w1.x + bb1.x);
  h1.y = tobf((val[5] - mu) * rsv * w1.y + bb1.y);
  h1.z = tobf((val[6] - mu) * rsv * w1.z + bb1.z);
  h1.w = tobf((val[7] - mu) * rsv * w1.w + bb1.w);
  unsigned short* hrow = h2b + ((size_t)b * SS + q0 + row) * DD + cb;
  *(ushort4*)hrow = h0;
  *(ushort4*)(hrow + 4) = h1;
}

// ---------------- weight transpose+convert: src[K][N] f32 -> dst[N][K] bf16 -
__global__ void wconv_kernel(const float* __restrict__ src, unsigned short* __restrict__ dst,
                             int K, int N) {
  int k = blockIdx.x;
  for (int n = threadIdx.x; n < N; n += 256)
    dst[(size_t)n * K + k] = tobf(src[(size_t)k * N + n]);
}

// ---------------- FFN1: [16384,256] @ [256,1024] + b1, relu -> bf16 ---------
__global__ void ffn1_kernel(const unsigned short* __restrict__ A,
                            const unsigned short* __restrict__ Bt,
                            const float* __restrict__ bias,
                            unsigned short* __restrict__ Out) {
  int bid = blockIdx.x;
  int nb = bid & 7, mb = bid >> 3;
  int wid = threadIdx.x >> 6, lane = threadIdx.x & 63;
  int wm = wid >> 1, wn = wid & 1;
  int lr = lane & 15, lg = lane >> 4;
  int m0 = mb * 128 + wm * 64;
  int n0 = nb * 128 + wn * 64;
  f32x4 acc[4][4];
#pragma unroll
  for (int i = 0; i < 4; ++i)
#pragma unroll
    for (int j = 0; j < 4; ++j) acc[i][j] = (f32x4){0.f, 0.f, 0.f, 0.f};
#pragma unroll
  for (int kc = 0; kc < 8; ++kc) {
    bf16x8 am[4], bn[4];
#pragma unroll
    for (int i = 0; i < 4; ++i) {
      U16 u; u.u = *(const uint4*)(A + (size_t)(m0 + i * 16 + lr) * 256 + kc * 32 + lg * 8);
      am[i] = u.b;
      U16 v; v.u = *(const uint4*)(Bt + (size_t)(n0 + i * 16 + lr) * 256 + kc * 32 + lg * 8);
      bn[i] = v.b;
    }
#pragma unroll
    for (int i = 0; i < 4; ++i)
#pragma unroll
      for (int j = 0; j < 4; ++j)
        acc[i][j] = __builtin_amdgcn_mfma_f32_16x16x32_bf16(am[i], bn[j], acc[i][j], 0, 0, 0);
  }
#pragma unroll
  for (int i = 0; i < 4; ++i)
#pragma unroll
    for (int j = 0; j < 4; ++j)
#pragma unroll
      for (int r = 0; r < 4; ++r) {
        int m = m0 + i * 16 + lg * 4 + r;
        int n = n0 + j * 16 + lr;
        float v = fmaxf(acc[i][j][r] + bias[n], 0.f);
        Out[(size_t)m * 1024 + n] = tobf(v);
      }
}

// ---------------- FFN2: [16384,1024] @ [1024,256] + b2 + residual (f32) -----
__global__ void ffn2_kernel(const unsigned short* __restrict__ A,
                            const unsigned short* __restrict__ Bt,
                            const float* __restrict__ bias,
                            float* __restrict__ Out) {
  int bid = blockIdx.x;
  int nb = bid & 1, mb = bid >> 1;
  int wid = threadIdx.x >> 6, lane = threadIdx.x & 63;
  int wm = wid >> 1, wn = wid & 1;
  int lr = lane & 15, lg = lane >> 4;
  int m0 = mb * 128 + wm * 64;
  int n0 = nb * 128 + wn * 64;
  f32x4 acc[4][4];
#pragma unroll
  for (int i = 0; i < 4; ++i)
#pragma unroll
    for (int j = 0; j < 4; ++j) acc[i][j] = (f32x4){0.f, 0.f, 0.f, 0.f};
  for (int kc = 0; kc < 32; ++kc) {
    bf16x8 am[4], bn[4];
#pragma unroll
    for (int i = 0; i < 4; ++i) {
      U16 u; u.u = *(const uint4*)(A + (size_t)(m0 + i * 16 + lr) * 1024 + kc * 32 + lg * 8);
      am[i] = u.b;
      U16 v; v.u = *(const uint4*)(Bt + (size_t)(n0 + i * 16 + lr) * 1024 + kc * 32 + lg * 8);
      bn[i] = v.b;
    }
#pragma unroll
    for (int i = 0; i < 4; ++i)
#pragma unroll
      for (int j = 0; j < 4; ++j)
        acc[i][j] = __builtin_amdgcn_mfma_f32_16x16x32_bf16(am[i], bn[j], acc[i][j], 0, 0, 0);
  }
#pragma unroll
  for (int i = 0; i < 4; ++i)
#pragma unroll
    for (int j = 0; j < 4; ++j)
#pragma unroll
      for (int r = 0; r < 4; ++r) {
        int m = m0 + i * 16 + lg * 4 + r;
        int n = n0 + j * 16 + lr;
        Out[(size_t)m * 256 + n] += acc[i][j][r] + bias[n];
      }
}

extern "C" void kernel_launch(void* const* d_in, const int* in_sizes, int n_in,
                              void* d_out, int out_size, void* d_ws, size_t ws_size,
                              hipStream_t stream) {
  const float* x     = (const float*)d_in[0];
  const float* r_mat = (const float*)d_in[1];
  const float* attn  = (const float*)d_in[2];
  const float* pad   = (const float*)d_in[3];
  const float* ln1w  = (const float*)d_in[4];
  const float* ln1b  = (const float*)d_in[5];
  const float* ln2w  = (const float*)d_in[6];
  const float* ln2b  = (const float*)d_in[7];
  const float* w1    = (const float*)d_in[8];
  const float* b1    = (const float*)d_in[9];
  const float* w2    = (const float*)d_in[10];
  const float* b2    = (const float*)d_in[11];
  float* out = (float*)d_out;

  uint8_t* ws = (uint8_t*)d_ws;
  unsigned short* hb   = (unsigned short*)(ws + 0);          // 8,388,608
  unsigned short* hbT  = (unsigned short*)(ws + 8388608);    // 8,388,608
  unsigned short* h2b  = (unsigned short*)(ws + 16777216);   // 8,388,608
  unsigned short* w1bT = (unsigned short*)(ws + 25165824);   // 524,288
  unsigned short* w2bT = (unsigned short*)(ws + 25690112);   // 524,288
  float* m1            = (float*)(ws + 26214400);            // 65,536
  float* is1           = (float*)(ws + 26279936);            // 65,536
  unsigned short* t    = (unsigned short*)(ws + 26345472);   // 33,554,432

  hipLaunchKernelGGL(ln_kernel, dim3(4096), dim3(256), 0, stream, x, ln1w, ln1b, hb);
  hipLaunchKernelGGL(transpose_kernel, dim3(1024), dim3(256), 0, stream, hb, hbT);
  hipLaunchKernelGGL(rowstats_kernel, dim3(4096), dim3(256), 0, stream, r_mat, attn, pad, m1, is1);
  hipLaunchKernelGGL(flash_kernel, dim3(1024), dim3(512), 0, stream,
                     hb, hbT, x, r_mat, attn, pad, m1, is1, ln2w, ln2b, out, h2b);
  hipLaunchKernelGGL(wconv_kernel, dim3(256), dim3(256), 0, stream, w1, w1bT, 256, 1024);
  hipLaunchKernelGGL(wconv_kernel, dim3(1024), dim3(256), 0, stream, w2, w2bT, 1024, 256);
  hipLaunchKernelGGL(ffn1_kernel, dim3(1024), dim3(256), 0, stream, h2b, w1bT, b1, t);
  hipLaunchKernelGGL(ffn2_kernel, dim3(256), dim3(256), 0, stream, t, w2bT, b2, out);
}

// Round 4
// 433.538 us; speedup vs baseline: 1.5911x; 1.0532x over previous
//
#include <hip/hip_runtime.h>
#include <stdint.h>

#define NB 8
#define SS 2048
#define DD 256
#define NEGV -1e9f

typedef __attribute__((ext_vector_type(8))) __bf16 bf16x8;
typedef __attribute__((ext_vector_type(4))) float f32x4;

union U16 { uint4 u; bf16x8 b; unsigned short us[8]; };

__device__ __forceinline__ unsigned short tobf(float v) {
  union { float f; uint32_t u; } c; c.f = v;
  uint32_t r = (c.u + 0x7fffu + ((c.u >> 16) & 1u)) >> 16;
  return (unsigned short)r;
}
__device__ __forceinline__ float frombf(unsigned short v) {
  union { uint32_t u; float f; } c; c.u = ((uint32_t)v) << 16;
  return c.f;
}

// ---------------- LayerNorm (f32 in -> bf16 out), one wave per row ----------
__global__ void ln_kernel(const float* __restrict__ in, const float* __restrict__ w,
                          const float* __restrict__ bparm, unsigned short* __restrict__ outb) {
  int row = blockIdx.x * 4 + (threadIdx.x >> 6);
  int lane = threadIdx.x & 63;
  const float* xr = in + (size_t)row * DD;
  float4 v = *(const float4*)(xr + lane * 4);
  float s = v.x + v.y + v.z + v.w;
  float s2 = v.x * v.x + v.y * v.y + v.z * v.z + v.w * v.w;
#pragma unroll
  for (int m = 1; m < 64; m <<= 1) { s += __shfl_xor(s, m); s2 += __shfl_xor(s2, m); }
  float mu = s * (1.f / DD);
  float var = s2 * (1.f / DD) - mu * mu;
  float rs = rsqrtf(var + 1e-5f);
  float4 wv = *(const float4*)(w + lane * 4);
  float4 bv = *(const float4*)(bparm + lane * 4);
  ushort4 o;
  o.x = tobf((v.x - mu) * rs * wv.x + bv.x);
  o.y = tobf((v.y - mu) * rs * wv.y + bv.y);
  o.z = tobf((v.z - mu) * rs * wv.z + bv.z);
  o.w = tobf((v.w - mu) * rs * wv.w + bv.w);
  *(ushort4*)(outb + (size_t)row * DD + lane * 4) = o;
}

// ---------------- bf16 [B,S,D] -> [B,D,S] transpose, 64x64 LDS tiles --------
__global__ void transpose_kernel(const unsigned short* __restrict__ in,
                                 unsigned short* __restrict__ out) {
  __shared__ unsigned short tile[64][72];
  int bid = blockIdx.x;
  int b = bid >> 7;
  int rest = bid & 127;
  int st = rest >> 2, dt = rest & 3;
  int s0 = st * 64, d0 = dt * 64;
  int t = threadIdx.x;
  int r = t >> 2, cs = (t & 3) * 16;
  const unsigned short* src = in + ((size_t)b * SS + s0 + r) * DD + d0 + cs;
  *(uint4*)&tile[r][cs] = *(const uint4*)src;
  *(uint4*)&tile[r][cs + 8] = *(const uint4*)(src + 8);
  __syncthreads();
  union { unsigned short us[16]; uint4 u[2]; } tmp;
  int dr = t >> 2, sseg = (t & 3) * 16;
#pragma unroll
  for (int j = 0; j < 16; ++j) tmp.us[j] = tile[sseg + j][dr];
  unsigned short* dst = out + ((size_t)b * DD + d0 + dr) * SS + s0 + sseg;
  *(uint4*)dst = tmp.u[0];
  *(uint4*)(dst + 8) = tmp.u[1];
}

// ---------------- rmprep: masked softmax of r_mat -> bf16 MFMA-layout tiles -
// block = (b, qt): 16 q-rows. Output tile (qt,kt): 64 lanes x 8 bf16 laid out
// exactly as flash's score C-fragment: us[r]   = P[q0+4*lg+r][k0+lr],
//                                       us[4+r] = P[q0+4*lg+r][k0+16+lr].
__global__ __launch_bounds__(512) void rmprep_kernel(
    const float* __restrict__ r_mat,
    const float* __restrict__ attn,
    const float* __restrict__ pad,
    unsigned short* __restrict__ smr) {
  __shared__ unsigned short ldsP16[16][2052];
  int bid = blockIdx.x;
  int b = bid & 7, qt = bid >> 3;
  int q0 = qt * 16;
  int w = threadIdx.x >> 6, lane = threadIdx.x & 63;
  const float* prow = pad + (size_t)b * SS;
  float4 padv[8];
#pragma unroll
  for (int i = 0; i < 8; ++i) padv[i] = *(const float4*)(prow + i * 256 + lane * 4);

#pragma unroll
  for (int rr = 0; rr < 2; ++rr) {
    int row = w * 2 + rr;
    int q = q0 + row;
    const float* rrow = r_mat + ((size_t)b * SS + q) * SS;
    const float* arow = attn + (size_t)q * SS;
    float v[32];
    float mx = -__builtin_inff();
#pragma unroll
    for (int i = 0; i < 8; ++i) {
      int c = i * 256 + lane * 4;
      float4 rv = *(const float4*)(rrow + c);
      float4 av = *(const float4*)(arow + c);
      float v0 = (padv[i].x == 0.f || av.x == 0.f) ? NEGV : rv.x;
      float v1 = (padv[i].y == 0.f || av.y == 0.f) ? NEGV : rv.y;
      float v2 = (padv[i].z == 0.f || av.z == 0.f) ? NEGV : rv.z;
      float v3 = (padv[i].w == 0.f || av.w == 0.f) ? NEGV : rv.w;
      v[i * 4 + 0] = v0; v[i * 4 + 1] = v1; v[i * 4 + 2] = v2; v[i * 4 + 3] = v3;
      mx = fmaxf(mx, fmaxf(fmaxf(v0, v1), fmaxf(v2, v3)));
    }
#pragma unroll
    for (int m = 1; m < 64; m <<= 1) mx = fmaxf(mx, __shfl_xor(mx, m));
    float sum = 0.f;
#pragma unroll
    for (int j = 0; j < 32; ++j) { v[j] = __expf(v[j] - mx); sum += v[j]; }
#pragma unroll
    for (int m = 1; m < 64; m <<= 1) sum += __shfl_xor(sum, m);
    float inv = 1.f / sum;
#pragma unroll
    for (int i = 0; i < 8; ++i) {
      ushort4 o;
      o.x = tobf(v[i * 4 + 0] * inv);
      o.y = tobf(v[i * 4 + 1] * inv);
      o.z = tobf(v[i * 4 + 2] * inv);
      o.w = tobf(v[i * 4 + 3] * inv);
      *(ushort4*)&ldsP16[row][i * 256 + lane * 4] = o;
    }
  }
  __syncthreads();

  // emission: 64 k-tiles, wave w emits kt = w*8 .. w*8+7
  int lr = lane & 15, lg = lane >> 4;
  unsigned short* base = smr + (size_t)(b * 128 + qt) * 64 * 512;
#pragma unroll
  for (int t = 0; t < 8; ++t) {
    int kt = w * 8 + t;
    int k0 = kt * 32;
    U16 o;
#pragma unroll
    for (int r = 0; r < 4; ++r) {
      int qloc = lg * 4 + r;
      o.us[r] = ldsP16[qloc][k0 + lr];
      o.us[4 + r] = ldsP16[qloc][k0 + 16 + lr];
    }
    *(uint4*)(base + (size_t)kt * 512 + lane * 8) = o.u;
  }
}

// ---------------- flash attention: 4 waves/block split-K, no fences ---------
// wave w handles kt in [w*16, w*16+16) for one 16-row q tile.
// Scores = QK^T/16 + smr(tile, pre-laid-out). Defer-max (THR=8) skips
// acc rescale on most iterations. Merge fuses residual + LN2.
__global__ __launch_bounds__(256) void flash_kernel(
    const unsigned short* __restrict__ hb,
    const unsigned short* __restrict__ hbT,
    const unsigned short* __restrict__ smr,
    const float* __restrict__ x,
    const float* __restrict__ ln2w,
    const float* __restrict__ ln2b,
    float* __restrict__ out,
    unsigned short* __restrict__ h2b) {
  __shared__ __align__(16) unsigned short Obuf[4][16][264];
  __shared__ float Mbuf[4][16];
  __shared__ float Lbuf[4][16];

  int bid = blockIdx.x;
  int b = bid & 7, qt = bid >> 3;
  int q0 = qt * 16;
  int w = threadIdx.x >> 6;
  int lane = threadIdx.x & 63;
  int lr = lane & 15, lg = lane >> 4;

  const unsigned short* hbB = hb + (size_t)b * SS * DD;
  const unsigned short* hbTB = hbT + (size_t)b * DD * SS;
  const unsigned short* smrB = smr + (size_t)(b * 128 + qt) * 64 * 512;

  unsigned short (*ldsP)[48] = (unsigned short (*)[48])&Obuf[w][0][0];

  bf16x8 aq[8];
#pragma unroll
  for (int dc = 0; dc < 8; ++dc) {
    U16 u; u.u = *(const uint4*)(hbB + (size_t)(q0 + lr) * DD + dc * 32 + lg * 8);
    aq[dc] = u.b;
  }
  float mrun[4], lrun[4];
#pragma unroll
  for (int r = 0; r < 4; ++r) { mrun[r] = -__builtin_inff(); lrun[r] = 0.f; }
  f32x4 acc[16];
#pragma unroll
  for (int d = 0; d < 16; ++d) acc[d] = (f32x4){0.f, 0.f, 0.f, 0.f};

  for (int kt = w * 16; kt < w * 16 + 16; ++kt) {
    int k0 = kt * 32;
    f32x4 sa = (f32x4){0.f, 0.f, 0.f, 0.f};
    f32x4 sb = (f32x4){0.f, 0.f, 0.f, 0.f};
#pragma unroll
    for (int dc = 0; dc < 8; ++dc) {
      U16 u0; u0.u = *(const uint4*)(hbB + (size_t)(k0 + lr) * DD + dc * 32 + lg * 8);
      U16 u1; u1.u = *(const uint4*)(hbB + (size_t)(k0 + 16 + lr) * DD + dc * 32 + lg * 8);
      sa = __builtin_amdgcn_mfma_f32_16x16x32_bf16(aq[dc], u0.b, sa, 0, 0, 0);
      sb = __builtin_amdgcn_mfma_f32_16x16x32_bf16(aq[dc], u1.b, sb, 0, 0, 0);
    }
    U16 sv; sv.u = *(const uint4*)(smrB + (size_t)kt * 512 + lane * 8);
    float sc0[4], sc1[4];
#pragma unroll
    for (int r = 0; r < 4; ++r) {
      sc0[r] = sa[r] * 0.0625f + frombf(sv.us[r]);
      sc1[r] = sb[r] * 0.0625f + frombf(sv.us[4 + r]);
    }
    float tm[4];
    float dmax = -__builtin_inff();
#pragma unroll
    for (int r = 0; r < 4; ++r) {
      float t = fmaxf(sc0[r], sc1[r]);
      t = fmaxf(t, __shfl_xor(t, 1));
      t = fmaxf(t, __shfl_xor(t, 2));
      t = fmaxf(t, __shfl_xor(t, 4));
      t = fmaxf(t, __shfl_xor(t, 8));
      tm[r] = t;
      dmax = fmaxf(dmax, t - mrun[r]);
    }
    if (__any(dmax > 8.f)) {
#pragma unroll
      for (int r = 0; r < 4; ++r) {
        float mnew = fmaxf(mrun[r], tm[r]);
        float a = __expf(mrun[r] - mnew);
        lrun[r] *= a;
        mrun[r] = mnew;
#pragma unroll
        for (int d = 0; d < 16; ++d) acc[d][r] *= a;
      }
    }
#pragma unroll
    for (int r = 0; r < 4; ++r) {
      float p0 = __expf(sc0[r] - mrun[r]);
      float p1 = __expf(sc1[r] - mrun[r]);
      float rs = p0 + p1;
      rs += __shfl_xor(rs, 1);
      rs += __shfl_xor(rs, 2);
      rs += __shfl_xor(rs, 4);
      rs += __shfl_xor(rs, 8);
      lrun[r] += rs;
      ldsP[lg * 4 + r][lr] = tobf(p0);
      ldsP[lg * 4 + r][16 + lr] = tobf(p1);
    }
    U16 pafrag; pafrag.u = *(const uint4*)&ldsP[lr][lg * 8];
#pragma unroll
    for (int d = 0; d < 16; ++d) {
      U16 bv; bv.u = *(const uint4*)(hbTB + (size_t)(d * 16 + lr) * SS + k0 + lg * 8);
      acc[d] = __builtin_amdgcn_mfma_f32_16x16x32_bf16(pafrag.b, bv.b, acc[d], 0, 0, 0);
    }
  }

  // ---- write partial state ----
#pragma unroll
  for (int d = 0; d < 16; ++d)
#pragma unroll
    for (int r = 0; r < 4; ++r)
      Obuf[w][lg * 4 + r][d * 16 + lr] = tobf(acc[d][r]);
  if (lr == 0) {
#pragma unroll
    for (int r = 0; r < 4; ++r) {
      Mbuf[w][lg * 4 + r] = mrun[r];
      Lbuf[w][lg * 4 + r] = lrun[r];
    }
  }
  __syncthreads();

  // ---- merge 4 partials: 256 threads, 16 rows x 16 cols each; fused LN2 ----
  int t = threadIdx.x;
  int row = t >> 4, cb = (t & 15) * 16;
  float mstar = -__builtin_inff();
  float mv[4];
#pragma unroll
  for (int w2 = 0; w2 < 4; ++w2) { mv[w2] = Mbuf[w2][row]; mstar = fmaxf(mstar, mv[w2]); }
  float L = 0.f;
  float wgt[4];
#pragma unroll
  for (int w2 = 0; w2 < 4; ++w2) {
    wgt[w2] = __expf(mv[w2] - mstar);
    L += wgt[w2] * Lbuf[w2][row];
  }
  float o[16];
#pragma unroll
  for (int j = 0; j < 16; ++j) o[j] = 0.f;
#pragma unroll
  for (int w2 = 0; w2 < 4; ++w2) {
    U16 p0, p1;
    p0.u = *(const uint4*)&Obuf[w2][row][cb];
    p1.u = *(const uint4*)&Obuf[w2][row][cb + 8];
#pragma unroll
    for (int j = 0; j < 8; ++j) {
      o[j] += wgt[w2] * frombf(p0.us[j]);
      o[8 + j] += wgt[w2] * frombf(p1.us[j]);
    }
  }
  float invL = 1.f / L;
  const float* xr = x + ((size_t)b * SS + q0 + row) * DD + cb;
  float* orow = out + ((size_t)b * SS + q0 + row) * DD + cb;
  float val[16];
#pragma unroll
  for (int j = 0; j < 16; j += 4) {
    float4 xv = *(const float4*)(xr + j);
    val[j + 0] = o[j + 0] * invL + xv.x;
    val[j + 1] = o[j + 1] * invL + xv.y;
    val[j + 2] = o[j + 2] * invL + xv.z;
    val[j + 3] = o[j + 3] * invL + xv.w;
    float4 sv = {val[j], val[j + 1], val[j + 2], val[j + 3]};
    *(float4*)(orow + j) = sv;
  }
  // LN2 across the 16 threads holding this row
  float s = 0.f, s2 = 0.f;
#pragma unroll
  for (int j = 0; j < 16; ++j) { s += val[j]; s2 += val[j] * val[j]; }
#pragma unroll
  for (int m = 1; m < 16; m <<= 1) { s += __shfl_xor(s, m); s2 += __shfl_xor(s2, m); }
  float mu = s * (1.f / DD);
  float var = s2 * (1.f / DD) - mu * mu;
  float rsv = rsqrtf(var + 1e-5f);
  unsigned short* hrow = h2b + ((size_t)b * SS + q0 + row) * DD + cb;
#pragma unroll
  for (int j = 0; j < 16; j += 8) {
    float4 wv0 = *(const float4*)(ln2w + cb + j);
    float4 wv1 = *(const float4*)(ln2w + cb + j + 4);
    float4 bv0 = *(const float4*)(ln2b + cb + j);
    float4 bv1 = *(const float4*)(ln2b + cb + j + 4);
    U16 h;
    h.us[0] = tobf((val[j + 0] - mu) * rsv * wv0.x + bv0.x);
    h.us[1] = tobf((val[j + 1] - mu) * rsv * wv0.y + bv0.y);
    h.us[2] = tobf((val[j + 2] - mu) * rsv * wv0.z + bv0.z);
    h.us[3] = tobf((val[j + 3] - mu) * rsv * wv0.w + bv0.w);
    h.us[4] = tobf((val[j + 4] - mu) * rsv * wv1.x + bv1.x);
    h.us[5] = tobf((val[j + 5] - mu) * rsv * wv1.y + bv1.y);
    h.us[6] = tobf((val[j + 6] - mu) * rsv * wv1.z + bv1.z);
    h.us[7] = tobf((val[j + 7] - mu) * rsv * wv1.w + bv1.w);
    *(uint4*)(hrow + j) = h.u;
  }
}

// ---------------- weight transpose+convert: src[K][N] f32 -> dst[N][K] bf16 -
__global__ void wconv_kernel(const float* __restrict__ src, unsigned short* __restrict__ dst,
                             int K, int N) {
  int k = blockIdx.x;
  for (int n = threadIdx.x; n < N; n += 256)
    dst[(size_t)n * K + k] = tobf(src[(size_t)k * N + n]);
}

// ---------------- FFN1: [16384,256] @ [256,1024] + b1, relu -> bf16 ---------
__global__ void ffn1_kernel(const unsigned short* __restrict__ A,
                            const unsigned short* __restrict__ Bt,
                            const float* __restrict__ bias,
                            unsigned short* __restrict__ Out) {
  int bid = blockIdx.x;
  int nb = bid & 7, mb = bid >> 3;
  int wid = threadIdx.x >> 6, lane = threadIdx.x & 63;
  int wm = wid >> 1, wn = wid & 1;
  int lr = lane & 15, lg = lane >> 4;
  int m0 = mb * 128 + wm * 64;
  int n0 = nb * 128 + wn * 64;
  f32x4 acc[4][4];
#pragma unroll
  for (int i = 0; i < 4; ++i)
#pragma unroll
    for (int j = 0; j < 4; ++j) acc[i][j] = (f32x4){0.f, 0.f, 0.f, 0.f};
#pragma unroll
  for (int kc = 0; kc < 8; ++kc) {
    bf16x8 am[4], bn[4];
#pragma unroll
    for (int i = 0; i < 4; ++i) {
      U16 u; u.u = *(const uint4*)(A + (size_t)(m0 + i * 16 + lr) * 256 + kc * 32 + lg * 8);
      am[i] = u.b;
      U16 v; v.u = *(const uint4*)(Bt + (size_t)(n0 + i * 16 + lr) * 256 + kc * 32 + lg * 8);
      bn[i] = v.b;
    }
#pragma unroll
    for (int i = 0; i < 4; ++i)
#pragma unroll
      for (int j = 0; j < 4; ++j)
        acc[i][j] = __builtin_amdgcn_mfma_f32_16x16x32_bf16(am[i], bn[j], acc[i][j], 0, 0, 0);
  }
#pragma unroll
  for (int i = 0; i < 4; ++i)
#pragma unroll
    for (int j = 0; j < 4; ++j)
#pragma unroll
      for (int r = 0; r < 4; ++r) {
        int m = m0 + i * 16 + lg * 4 + r;
        int n = n0 + j * 16 + lr;
        float v = fmaxf(acc[i][j][r] + bias[n], 0.f);
        Out[(size_t)m * 1024 + n] = tobf(v);
      }
}

// ---------------- FFN2: [16384,1024] @ [1024,256] + b2 + residual (f32) -----
__global__ void ffn2_kernel(const unsigned short* __restrict__ A,
                            const unsigned short* __restrict__ Bt,
                            const float* __restrict__ bias,
                            float* __restrict__ Out) {
  int bid = blockIdx.x;
  int nb = bid & 1, mb = bid >> 1;
  int wid = threadIdx.x >> 6, lane = threadIdx.x & 63;
  int wm = wid >> 1, wn = wid & 1;
  int lr = lane & 15, lg = lane >> 4;
  int m0 = mb * 128 + wm * 64;
  int n0 = nb * 128 + wn * 64;
  f32x4 acc[4][4];
#pragma unroll
  for (int i = 0; i < 4; ++i)
#pragma unroll
    for (int j = 0; j < 4; ++j) acc[i][j] = (f32x4){0.f, 0.f, 0.f, 0.f};
  for (int kc = 0; kc < 32; ++kc) {
    bf16x8 am[4], bn[4];
#pragma unroll
    for (int i = 0; i < 4; ++i) {
      U16 u; u.u = *(const uint4*)(A + (size_t)(m0 + i * 16 + lr) * 1024 + kc * 32 + lg * 8);
      am[i] = u.b;
      U16 v; v.u = *(const uint4*)(Bt + (size_t)(n0 + i * 16 + lr) * 1024 + kc * 32 + lg * 8);
      bn[i] = v.b;
    }
#pragma unroll
    for (int i = 0; i < 4; ++i)
#pragma unroll
      for (int j = 0; j < 4; ++j)
        acc[i][j] = __builtin_amdgcn_mfma_f32_16x16x32_bf16(am[i], bn[j], acc[i][j], 0, 0, 0);
  }
#pragma unroll
  for (int i = 0; i < 4; ++i)
#pragma unroll
    for (int j = 0; j < 4; ++j)
#pragma unroll
      for (int r = 0; r < 4; ++r) {
        int m = m0 + i * 16 + lg * 4 + r;
        int n = n0 + j * 16 + lr;
        Out[(size_t)m * 256 + n] += acc[i][j][r] + bias[n];
      }
}

extern "C" void kernel_launch(void* const* d_in, const int* in_sizes, int n_in,
                              void* d_out, int out_size, void* d_ws, size_t ws_size,
                              hipStream_t stream) {
  const float* x     = (const float*)d_in[0];
  const float* r_mat = (const float*)d_in[1];
  const float* attn  = (const float*)d_in[2];
  const float* pad   = (const float*)d_in[3];
  const float* ln1w  = (const float*)d_in[4];
  const float* ln1b  = (const float*)d_in[5];
  const float* ln2w  = (const float*)d_in[6];
  const float* ln2b  = (const float*)d_in[7];
  const float* w1    = (const float*)d_in[8];
  const float* b1    = (const float*)d_in[9];
  const float* w2    = (const float*)d_in[10];
  const float* b2    = (const float*)d_in[11];
  float* out = (float*)d_out;

  uint8_t* ws = (uint8_t*)d_ws;
  unsigned short* hb   = (unsigned short*)(ws + 0);          // 8 MB
  unsigned short* hbT  = (unsigned short*)(ws + 8388608);    // 8 MB
  unsigned short* h2b  = (unsigned short*)(ws + 16777216);   // 8 MB
  unsigned short* w1bT = (unsigned short*)(ws + 25165824);   // 0.5 MB
  unsigned short* w2bT = (unsigned short*)(ws + 25690112);   // 0.5 MB
  unsigned short* smr  = (unsigned short*)(ws + 33554432);   // 64 MB (bf16 S x S)
  unsigned short* t    = smr;                                // FFN intermediate aliases smr
                                                             // (smr dead after flash)

  hipLaunchKernelGGL(ln_kernel, dim3(4096), dim3(256), 0, stream, x, ln1w, ln1b, hb);
  hipLaunchKernelGGL(transpose_kernel, dim3(1024), dim3(256), 0, stream, hb, hbT);
  hipLaunchKernelGGL(rmprep_kernel, dim3(1024), dim3(512), 0, stream, r_mat, attn, pad, smr);
  hipLaunchKernelGGL(flash_kernel, dim3(1024), dim3(256), 0, stream,
                     hb, hbT, smr, x, ln2w, ln2b, out, h2b);
  hipLaunchKernelGGL(wconv_kernel, dim3(256), dim3(256), 0, stream, w1, w1bT, 256, 1024);
  hipLaunchKernelGGL(wconv_kernel, dim3(1024), dim3(256), 0, stream, w2, w2bT, 1024, 256);
  hipLaunchKernelGGL(ffn1_kernel, dim3(1024), dim3(256), 0, stream, h2b, w1bT, b1, t);
  hipLaunchKernelGGL(ffn2_kernel, dim3(256), dim3(256), 0, stream, t, w2bT, b2, out);
}

// Round 5
// 299.014 us; speedup vs baseline: 2.3069x; 1.4499x over previous
//
#include <hip/hip_runtime.h>
#include <stdint.h>

#define NB 8
#define SS 2048
#define DD 256
#define NEGV -1e9f

typedef __attribute__((ext_vector_type(8))) __bf16 bf16x8;
typedef __attribute__((ext_vector_type(4))) float f32x4;

union U16 { uint4 u; bf16x8 b; unsigned short us[8]; };

__device__ __forceinline__ unsigned short tobf(float v) {
  union { float f; uint32_t u; } c; c.f = v;
  uint32_t r = (c.u + 0x7fffu + ((c.u >> 16) & 1u)) >> 16;
  return (unsigned short)r;
}
__device__ __forceinline__ float frombf(unsigned short v) {
  union { uint32_t u; float f; } c; c.u = ((uint32_t)v) << 16;
  return c.f;
}

// ---------------- LayerNorm (f32 in -> bf16 out), one wave per row ----------
__global__ void ln_kernel(const float* __restrict__ in, const float* __restrict__ w,
                          const float* __restrict__ bparm, unsigned short* __restrict__ outb) {
  int row = blockIdx.x * 4 + (threadIdx.x >> 6);
  int lane = threadIdx.x & 63;
  const float* xr = in + (size_t)row * DD;
  float4 v = *(const float4*)(xr + lane * 4);
  float s = v.x + v.y + v.z + v.w;
  float s2 = v.x * v.x + v.y * v.y + v.z * v.z + v.w * v.w;
#pragma unroll
  for (int m = 1; m < 64; m <<= 1) { s += __shfl_xor(s, m); s2 += __shfl_xor(s2, m); }
  float mu = s * (1.f / DD);
  float var = s2 * (1.f / DD) - mu * mu;
  float rs = rsqrtf(var + 1e-5f);
  float4 wv = *(const float4*)(w + lane * 4);
  float4 bv = *(const float4*)(bparm + lane * 4);
  ushort4 o;
  o.x = tobf((v.x - mu) * rs * wv.x + bv.x);
  o.y = tobf((v.y - mu) * rs * wv.y + bv.y);
  o.z = tobf((v.z - mu) * rs * wv.z + bv.z);
  o.w = tobf((v.w - mu) * rs * wv.w + bv.w);
  *(ushort4*)(outb + (size_t)row * DD + lane * 4) = o;
}

// ---------------- bf16 [B,S,D] -> [B,D,S] transpose, 64x64 LDS tiles --------
__global__ void transpose_kernel(const unsigned short* __restrict__ in,
                                 unsigned short* __restrict__ out) {
  __shared__ unsigned short tile[64][72];
  int bid = blockIdx.x;
  int b = bid >> 7;
  int rest = bid & 127;
  int st = rest >> 2, dt = rest & 3;
  int s0 = st * 64, d0 = dt * 64;
  int t = threadIdx.x;
  int r = t >> 2, cs = (t & 3) * 16;
  const unsigned short* src = in + ((size_t)b * SS + s0 + r) * DD + d0 + cs;
  *(uint4*)&tile[r][cs] = *(const uint4*)src;
  *(uint4*)&tile[r][cs + 8] = *(const uint4*)(src + 8);
  __syncthreads();
  union { unsigned short us[16]; uint4 u[2]; } tmp;
  int dr = t >> 2, sseg = (t & 3) * 16;
#pragma unroll
  for (int j = 0; j < 16; ++j) tmp.us[j] = tile[sseg + j][dr];
  unsigned short* dst = out + ((size_t)b * DD + d0 + dr) * SS + s0 + sseg;
  *(uint4*)dst = tmp.u[0];
  *(uint4*)(dst + 8) = tmp.u[1];
}

// ---------------- QK^T GEMM: S[b,q,k] = bf16( (h h^T) / 16 ) ----------------
// per batch M=N=2048, K=256. 128x128 tiles, 4 waves (2x2), 64x64 per wave.
__global__ __launch_bounds__(256) void qk_kernel(
    const unsigned short* __restrict__ hb,
    unsigned short* __restrict__ S) {
  int bid = blockIdx.x;
  int b = bid & 7;
  int tile = bid >> 3;             // 0..255
  int mb = tile >> 4, nb = tile & 15;
  int wid = threadIdx.x >> 6, lane = threadIdx.x & 63;
  int wm = wid >> 1, wn = wid & 1;
  int lr = lane & 15, lg = lane >> 4;
  int m0 = mb * 128 + wm * 64;
  int n0 = nb * 128 + wn * 64;
  const unsigned short* A = hb + (size_t)b * SS * DD;
  f32x4 acc[4][4];
#pragma unroll
  for (int i = 0; i < 4; ++i)
#pragma unroll
    for (int j = 0; j < 4; ++j) acc[i][j] = (f32x4){0.f, 0.f, 0.f, 0.f};
#pragma unroll
  for (int kc = 0; kc < 8; ++kc) {
    bf16x8 am[4], bn[4];
#pragma unroll
    for (int i = 0; i < 4; ++i) {
      U16 u; u.u = *(const uint4*)(A + (size_t)(m0 + i * 16 + lr) * DD + kc * 32 + lg * 8);
      am[i] = u.b;
      U16 v; v.u = *(const uint4*)(A + (size_t)(n0 + i * 16 + lr) * DD + kc * 32 + lg * 8);
      bn[i] = v.b;
    }
#pragma unroll
    for (int i = 0; i < 4; ++i)
#pragma unroll
      for (int j = 0; j < 4; ++j)
        acc[i][j] = __builtin_amdgcn_mfma_f32_16x16x32_bf16(am[i], bn[j], acc[i][j], 0, 0, 0);
  }
  unsigned short* Sb = S + (size_t)b * SS * SS;
#pragma unroll
  for (int i = 0; i < 4; ++i)
#pragma unroll
    for (int j = 0; j < 4; ++j)
#pragma unroll
      for (int r = 0; r < 4; ++r) {
        int m = m0 + i * 16 + lg * 4 + r;
        int n = n0 + j * 16 + lr;
        Sb[(size_t)m * SS + n] = tobf(acc[i][j][r] * 0.0625f);
      }
}

// ---------------- fused row pass: P = softmax(S + softmax(mask(r_mat))) -----
// one wave per row; S (bf16 qk/16) overwritten in place with P (bf16).
__global__ __launch_bounds__(256) void smfuse_kernel(
    const float* __restrict__ r_mat,
    const float* __restrict__ attn,
    const float* __restrict__ pad,
    unsigned short* __restrict__ S) {
  int row = blockIdx.x * 4 + (threadIdx.x >> 6);
  int lane = threadIdx.x & 63;
  int b = row >> 11, q = row & 2047;
  const float* rrow = r_mat + (size_t)row * SS;
  const float* arow = attn + (size_t)q * SS;
  const float* prow = pad + (size_t)b * SS;
  unsigned short* srow = S + (size_t)row * SS;

  // pass 1: masked r_mat, row softmax (values kept in registers)
  float rm[32];
  float mx = -__builtin_inff();
#pragma unroll
  for (int i = 0; i < 8; ++i) {
    int c = i * 256 + lane * 4;
    float4 rv = *(const float4*)(rrow + c);
    float4 av = *(const float4*)(arow + c);
    float4 pv = *(const float4*)(prow + c);
    float v0 = (pv.x == 0.f || av.x == 0.f) ? NEGV : rv.x;
    float v1 = (pv.y == 0.f || av.y == 0.f) ? NEGV : rv.y;
    float v2 = (pv.z == 0.f || av.z == 0.f) ? NEGV : rv.z;
    float v3 = (pv.w == 0.f || av.w == 0.f) ? NEGV : rv.w;
    rm[i * 4 + 0] = v0; rm[i * 4 + 1] = v1; rm[i * 4 + 2] = v2; rm[i * 4 + 3] = v3;
    mx = fmaxf(mx, fmaxf(fmaxf(v0, v1), fmaxf(v2, v3)));
  }
#pragma unroll
  for (int m = 1; m < 64; m <<= 1) mx = fmaxf(mx, __shfl_xor(mx, m));
  float sum = 0.f;
#pragma unroll
  for (int j = 0; j < 32; ++j) { rm[j] = __expf(rm[j] - mx); sum += rm[j]; }
#pragma unroll
  for (int m = 1; m < 64; m <<= 1) sum += __shfl_xor(sum, m);
  float inv = 1.f / sum;

  // pass 2: scores = S + smprob, row softmax, write P in place
  float sc[32];
  float mx2 = -__builtin_inff();
#pragma unroll
  for (int i = 0; i < 8; ++i) {
    int c = i * 256 + lane * 4;
    ushort4 sv = *(const ushort4*)(srow + c);
    float s0 = frombf(sv.x) + rm[i * 4 + 0] * inv;
    float s1 = frombf(sv.y) + rm[i * 4 + 1] * inv;
    float s2 = frombf(sv.z) + rm[i * 4 + 2] * inv;
    float s3 = frombf(sv.w) + rm[i * 4 + 3] * inv;
    sc[i * 4 + 0] = s0; sc[i * 4 + 1] = s1; sc[i * 4 + 2] = s2; sc[i * 4 + 3] = s3;
    mx2 = fmaxf(mx2, fmaxf(fmaxf(s0, s1), fmaxf(s2, s3)));
  }
#pragma unroll
  for (int m = 1; m < 64; m <<= 1) mx2 = fmaxf(mx2, __shfl_xor(mx2, m));
  float sum2 = 0.f;
#pragma unroll
  for (int j = 0; j < 32; ++j) { sc[j] = __expf(sc[j] - mx2); sum2 += sc[j]; }
#pragma unroll
  for (int m = 1; m < 64; m <<= 1) sum2 += __shfl_xor(sum2, m);
  float inv2 = 1.f / sum2;
#pragma unroll
  for (int i = 0; i < 8; ++i) {
    int c = i * 256 + lane * 4;
    ushort4 o;
    o.x = tobf(sc[i * 4 + 0] * inv2);
    o.y = tobf(sc[i * 4 + 1] * inv2);
    o.z = tobf(sc[i * 4 + 2] * inv2);
    o.w = tobf(sc[i * 4 + 3] * inv2);
    *(ushort4*)(srow + c) = o;
  }
}

// ---------------- PV GEMM: out[b,q,d] = P @ V + x (residual fused) ----------
// per batch M=2048, N=256, K=2048. A = P row-major, Bt = hbT (V^T layout).
__global__ __launch_bounds__(256) void pv_kernel(
    const unsigned short* __restrict__ P,
    const unsigned short* __restrict__ hbT,
    const float* __restrict__ x,
    float* __restrict__ out) {
  int bid = blockIdx.x;
  int b = bid & 7;
  int tile = bid >> 3;             // 0..31
  int mb = tile >> 1, nb = tile & 1;
  int wid = threadIdx.x >> 6, lane = threadIdx.x & 63;
  int wm = wid >> 1, wn = wid & 1;
  int lr = lane & 15, lg = lane >> 4;
  int m0 = mb * 128 + wm * 64;
  int n0 = nb * 128 + wn * 64;
  const unsigned short* A = P + (size_t)b * SS * SS;
  const unsigned short* Bt = hbT + (size_t)b * DD * SS;
  f32x4 acc[4][4];
#pragma unroll
  for (int i = 0; i < 4; ++i)
#pragma unroll
    for (int j = 0; j < 4; ++j) acc[i][j] = (f32x4){0.f, 0.f, 0.f, 0.f};
  for (int kc = 0; kc < 64; ++kc) {
    bf16x8 am[4], bn[4];
#pragma unroll
    for (int i = 0; i < 4; ++i) {
      U16 u; u.u = *(const uint4*)(A + (size_t)(m0 + i * 16 + lr) * SS + kc * 32 + lg * 8);
      am[i] = u.b;
      U16 v; v.u = *(const uint4*)(Bt + (size_t)(n0 + i * 16 + lr) * SS + kc * 32 + lg * 8);
      bn[i] = v.b;
    }
#pragma unroll
    for (int i = 0; i < 4; ++i)
#pragma unroll
      for (int j = 0; j < 4; ++j)
        acc[i][j] = __builtin_amdgcn_mfma_f32_16x16x32_bf16(am[i], bn[j], acc[i][j], 0, 0, 0);
  }
#pragma unroll
  for (int i = 0; i < 4; ++i)
#pragma unroll
    for (int j = 0; j < 4; ++j)
#pragma unroll
      for (int r = 0; r < 4; ++r) {
        int m = m0 + i * 16 + lg * 4 + r;
        int n = n0 + j * 16 + lr;
        size_t idx = ((size_t)b * SS + m) * DD + n;
        out[idx] = acc[i][j][r] + x[idx];
      }
}

// ---------------- weight transpose+convert: src[K][N] f32 -> dst[N][K] bf16 -
__global__ void wconv_kernel(const float* __restrict__ src, unsigned short* __restrict__ dst,
                             int K, int N) {
  int k = blockIdx.x;
  for (int n = threadIdx.x; n < N; n += 256)
    dst[(size_t)n * K + k] = tobf(src[(size_t)k * N + n]);
}

// ---------------- FFN1: [16384,256] @ [256,1024] + b1, relu -> bf16 ---------
__global__ __launch_bounds__(256) void ffn1_kernel(
    const unsigned short* __restrict__ A,
    const unsigned short* __restrict__ Bt,
    const float* __restrict__ bias,
    unsigned short* __restrict__ Out) {
  int bid = blockIdx.x;
  int nb = bid & 7, mb = bid >> 3;
  int wid = threadIdx.x >> 6, lane = threadIdx.x & 63;
  int wm = wid >> 1, wn = wid & 1;
  int lr = lane & 15, lg = lane >> 4;
  int m0 = mb * 128 + wm * 64;
  int n0 = nb * 128 + wn * 64;
  f32x4 acc[4][4];
#pragma unroll
  for (int i = 0; i < 4; ++i)
#pragma unroll
    for (int j = 0; j < 4; ++j) acc[i][j] = (f32x4){0.f, 0.f, 0.f, 0.f};
#pragma unroll
  for (int kc = 0; kc < 8; ++kc) {
    bf16x8 am[4], bn[4];
#pragma unroll
    for (int i = 0; i < 4; ++i) {
      U16 u; u.u = *(const uint4*)(A + (size_t)(m0 + i * 16 + lr) * 256 + kc * 32 + lg * 8);
      am[i] = u.b;
      U16 v; v.u = *(const uint4*)(Bt + (size_t)(n0 + i * 16 + lr) * 256 + kc * 32 + lg * 8);
      bn[i] = v.b;
    }
#pragma unroll
    for (int i = 0; i < 4; ++i)
#pragma unroll
      for (int j = 0; j < 4; ++j)
        acc[i][j] = __builtin_amdgcn_mfma_f32_16x16x32_bf16(am[i], bn[j], acc[i][j], 0, 0, 0);
  }
#pragma unroll
  for (int i = 0; i < 4; ++i)
#pragma unroll
    for (int j = 0; j < 4; ++j)
#pragma unroll
      for (int r = 0; r < 4; ++r) {
        int m = m0 + i * 16 + lg * 4 + r;
        int n = n0 + j * 16 + lr;
        float v = fmaxf(acc[i][j][r] + bias[n], 0.f);
        Out[(size_t)m * 1024 + n] = tobf(v);
      }
}

// ---------------- FFN2: [16384,1024] @ [1024,256] + b2 + residual (f32) -----
__global__ __launch_bounds__(256) void ffn2_kernel(
    const unsigned short* __restrict__ A,
    const unsigned short* __restrict__ Bt,
    const float* __restrict__ bias,
    float* __restrict__ Out) {
  int bid = blockIdx.x;
  int nb = bid & 1, mb = bid >> 1;
  int wid = threadIdx.x >> 6, lane = threadIdx.x & 63;
  int wm = wid >> 1, wn = wid & 1;
  int lr = lane & 15, lg = lane >> 4;
  int m0 = mb * 128 + wm * 64;
  int n0 = nb * 128 + wn * 64;
  f32x4 acc[4][4];
#pragma unroll
  for (int i = 0; i < 4; ++i)
#pragma unroll
    for (int j = 0; j < 4; ++j) acc[i][j] = (f32x4){0.f, 0.f, 0.f, 0.f};
  for (int kc = 0; kc < 32; ++kc) {
    bf16x8 am[4], bn[4];
#pragma unroll
    for (int i = 0; i < 4; ++i) {
      U16 u; u.u = *(const uint4*)(A + (size_t)(m0 + i * 16 + lr) * 1024 + kc * 32 + lg * 8);
      am[i] = u.b;
      U16 v; v.u = *(const uint4*)(Bt + (size_t)(n0 + i * 16 + lr) * 1024 + kc * 32 + lg * 8);
      bn[i] = v.b;
    }
#pragma unroll
    for (int i = 0; i < 4; ++i)
#pragma unroll
      for (int j = 0; j < 4; ++j)
        acc[i][j] = __builtin_amdgcn_mfma_f32_16x16x32_bf16(am[i], bn[j], acc[i][j], 0, 0, 0);
  }
#pragma unroll
  for (int i = 0; i < 4; ++i)
#pragma unroll
    for (int j = 0; j < 4; ++j)
#pragma unroll
      for (int r = 0; r < 4; ++r) {
        int m = m0 + i * 16 + lg * 4 + r;
        int n = n0 + j * 16 + lr;
        Out[(size_t)m * 256 + n] += acc[i][j][r] + bias[n];
      }
}

extern "C" void kernel_launch(void* const* d_in, const int* in_sizes, int n_in,
                              void* d_out, int out_size, void* d_ws, size_t ws_size,
                              hipStream_t stream) {
  const float* x     = (const float*)d_in[0];
  const float* r_mat = (const float*)d_in[1];
  const float* attn  = (const float*)d_in[2];
  const float* pad   = (const float*)d_in[3];
  const float* ln1w  = (const float*)d_in[4];
  const float* ln1b  = (const float*)d_in[5];
  const float* ln2w  = (const float*)d_in[6];
  const float* ln2b  = (const float*)d_in[7];
  const float* w1    = (const float*)d_in[8];
  const float* b1    = (const float*)d_in[9];
  const float* w2    = (const float*)d_in[10];
  const float* b2    = (const float*)d_in[11];
  float* out = (float*)d_out;

  uint8_t* ws = (uint8_t*)d_ws;
  unsigned short* hb   = (unsigned short*)(ws + 0);          // 8 MB
  unsigned short* hbT  = (unsigned short*)(ws + 8388608);    // 8 MB
  unsigned short* h2b  = (unsigned short*)(ws + 16777216);   // 8 MB
  unsigned short* w1bT = (unsigned short*)(ws + 25165824);   // 0.5 MB
  unsigned short* w2bT = (unsigned short*)(ws + 25690112);   // 0.5 MB
  unsigned short* S    = (unsigned short*)(ws + 26214400);   // 67 MB bf16 [B,S,S]
  unsigned short* t    = S;                                  // ffn1 out aliases S
                                                             // (S/P dead after pv)

  hipLaunchKernelGGL(ln_kernel, dim3(4096), dim3(256), 0, stream, x, ln1w, ln1b, hb);
  hipLaunchKernelGGL(transpose_kernel, dim3(1024), dim3(256), 0, stream, hb, hbT);
  hipLaunchKernelGGL(qk_kernel, dim3(2048), dim3(256), 0, stream, hb, S);
  hipLaunchKernelGGL(smfuse_kernel, dim3(4096), dim3(256), 0, stream, r_mat, attn, pad, S);
  hipLaunchKernelGGL(pv_kernel, dim3(256), dim3(256), 0, stream, S, hbT, x, out);
  hipLaunchKernelGGL(ln_kernel, dim3(4096), dim3(256), 0, stream, out, ln2w, ln2b, h2b);
  hipLaunchKernelGGL(wconv_kernel, dim3(256), dim3(256), 0, stream, w1, w1bT, 256, 1024);
  hipLaunchKernelGGL(wconv_kernel, dim3(1024), dim3(256), 0, stream, w2, w2bT, 1024, 256);
  hipLaunchKernelGGL(ffn1_kernel, dim3(1024), dim3(256), 0, stream, h2b, w1bT, b1, t);
  hipLaunchKernelGGL(ffn2_kernel, dim3(256), dim3(256), 0, stream, t, w2bT, b2, out);
}